// Round 1
// baseline (1855.298 us; speedup 1.0000x reference)
//
#include <hip/hip_runtime.h>
#include <math.h>

#define NSEQ 4096
#define DMODEL 512
#define NH 8
#define DHEAD 64
#define MFEAT 512
#define BHEADS 32            // B*H
#define ROWS_TOTAL 16384     // B*N

// data_normalizer = 64^-0.25 ; diag coeff = 0.5 * 64^-0.5
#define NORMALIZER 0.35355339059327373f
#define DIAG_C 0.0625f
#define KEPS 1e-4f

__device__ __forceinline__ float warpReduceSum(float v) {
#pragma unroll
    for (int off = 32; off > 0; off >>= 1) v += __shfl_xor(v, off);
    return v;
}

__device__ __forceinline__ void atomicMaxF(float* addr, float val) {
    int* ai = (int*)addr;
    int cur = __float_as_int(*addr);
    while (__int_as_float(cur) < val) {
        int prev = atomicCAS(ai, cur, __float_as_int(val));
        if (prev == cur) break;
        cur = prev;
    }
}

// ---------------------------------------------------------------------------
// C[r,c] = sum_k A[r,k] * W[c,k] + bias[c] (+ resid[r,c])
// A: [16384 x 512], W: [512 x 512]. Grid (8, 256), block 256.
// ---------------------------------------------------------------------------
__global__ __launch_bounds__(256)
void gemm_bt(const float* __restrict__ A, const float* __restrict__ W,
             const float* __restrict__ bias, const float* __restrict__ resid,
             float* __restrict__ C)
{
    __shared__ float As[16][68];   // transposed: [k][row], padded
    __shared__ float Bs[16][68];   // transposed: [k][col]
    const int tid = threadIdx.x;
    const int row0 = blockIdx.y << 6;
    const int col0 = blockIdx.x << 6;
    const int ty = tid >> 4, tx = tid & 15;
    float acc[4][4];
#pragma unroll
    for (int i = 0; i < 4; ++i)
#pragma unroll
        for (int j = 0; j < 4; ++j) acc[i][j] = 0.f;

    const int lr = tid >> 2;          // 0..63
    const int lk = (tid & 3) << 2;    // 0,4,8,12
    const float* Arow = A + (size_t)(row0 + lr) * DMODEL + lk;
    const float* Wrow = W + (size_t)(col0 + lr) * DMODEL + lk;

    for (int k0 = 0; k0 < DMODEL; k0 += 16) {
        float4 a = *(const float4*)(Arow + k0);
        float4 b = *(const float4*)(Wrow + k0);
        As[lk + 0][lr] = a.x; As[lk + 1][lr] = a.y; As[lk + 2][lr] = a.z; As[lk + 3][lr] = a.w;
        Bs[lk + 0][lr] = b.x; Bs[lk + 1][lr] = b.y; Bs[lk + 2][lr] = b.z; Bs[lk + 3][lr] = b.w;
        __syncthreads();
#pragma unroll
        for (int kk = 0; kk < 16; ++kk) {
            float4 av = *(const float4*)&As[kk][ty << 2];
            float4 bv = *(const float4*)&Bs[kk][tx << 2];
            float a4[4] = {av.x, av.y, av.z, av.w};
            float b4[4] = {bv.x, bv.y, bv.z, bv.w};
#pragma unroll
            for (int i = 0; i < 4; ++i)
#pragma unroll
                for (int j = 0; j < 4; ++j) acc[i][j] += a4[i] * b4[j];
        }
        __syncthreads();
    }

    const float4 bias4 = *(const float4*)(bias + col0 + (tx << 2));
#pragma unroll
    for (int i = 0; i < 4; ++i) {
        const int r = row0 + (ty << 2) + i;
        float4 o;
        o.x = acc[i][0] + bias4.x;
        o.y = acc[i][1] + bias4.y;
        o.z = acc[i][2] + bias4.z;
        o.w = acc[i][3] + bias4.w;
        if (resid) {
            const float4 rr = *(const float4*)(resid + (size_t)r * DMODEL + col0 + (tx << 2));
            o.x += rr.x; o.y += rr.y; o.z += rr.z; o.w += rr.w;
        }
        *(float4*)(C + (size_t)r * DMODEL + col0 + (tx << 2)) = o;
    }
}

// ---------------------------------------------------------------------------
// vsum[bh,e] = sum_n V[b,n,h*64+e]. Grid (32,16), block 64.
// ---------------------------------------------------------------------------
__global__ __launch_bounds__(64)
void vsum_kernel(const float* __restrict__ V, float* __restrict__ vsum)
{
    const int bh = blockIdx.x;
    const int b = bh >> 3, h = bh & 7;
    const int e = threadIdx.x;
    const int n0 = blockIdx.y << 8;
    const float* base = V + ((size_t)b * NSEQ + n0) * DMODEL + h * DHEAD + e;
    float s = 0.f;
    for (int n = 0; n < 256; ++n) s += base[(size_t)n * DMODEL];
    atomicAdd(&vsum[bh * DHEAD + e], s);
}

// ---------------------------------------------------------------------------
// k-side: accumulate ctx_pure[bh,m,e] = sum_n E[n,m]*v[n,e],
//         esum[bh,m] = sum_n E[n,m],  E = exp(kdash - diag)  (no global stab)
//         gmax = max over all kdash (atomic).
// Grid (32 bh, 4 m-tiles, 8 n-chunks), block 256.
// ---------------------------------------------------------------------------
__global__ __launch_bounds__(256)
void kside_kernel(const float* __restrict__ K, const float* __restrict__ V,
                  const float* __restrict__ projk,
                  float* __restrict__ ctxp, float* __restrict__ esum,
                  float* __restrict__ gmax)
{
    __shared__ float proj_s[128][68];
    __shared__ float k_s[32][64];
    __shared__ float v_s[32][64];
    __shared__ float kp_s[32][128];
    __shared__ float diag_s[32];
    __shared__ float wmax_s[4];

    const int tid = threadIdx.x;
    const int bh = blockIdx.x;
    const int b = bh >> 3, h = bh & 7;
    const int m0 = blockIdx.y << 7;
    const int n0 = blockIdx.z << 9;

    // stage 128x64 proj chunk (reused across all 512 rows)
#pragma unroll
    for (int t = 0; t < 8; ++t) {
        int lin = tid + (t << 8);
        int row = lin >> 4;
        int c4 = (lin & 15) << 2;
        *(float4*)&proj_s[row][c4] =
            *(const float4*)(projk + (size_t)(m0 + row) * DHEAD + c4);
    }

    const float* kbase = K + ((size_t)b * NSEQ) * DMODEL + h * DHEAD;
    const float* vbase = V + ((size_t)b * NSEQ) * DMODEL + h * DHEAD;

    float acc[4][8];
#pragma unroll
    for (int i = 0; i < 4; ++i)
#pragma unroll
        for (int j = 0; j < 8; ++j) acc[i][j] = 0.f;
    float esacc[4] = {0.f, 0.f, 0.f, 0.f};
    float lmax = -1e30f;

    const int eg = tid & 7;
    const int mg = tid >> 3;       // 0..31
    const int e0 = eg << 3;
    const int mloc = mg << 2;
    const int rt = tid >> 5;       // 0..7
    const int mt2 = tid & 31;
    const int w = tid >> 6, lane = tid & 63;

    __syncthreads();

    for (int it = 0; it < 16; ++it) {
        const int nb = n0 + (it << 5);
        // stage 32 rows of k and v
#pragma unroll
        for (int t = 0; t < 2; ++t) {
            int lin = tid + (t << 8);
            int row = lin >> 4;
            int c4 = (lin & 15) << 2;
            *(float4*)&k_s[row][c4] = *(const float4*)(kbase + (size_t)(nb + row) * DMODEL + c4);
            *(float4*)&v_s[row][c4] = *(const float4*)(vbase + (size_t)(nb + row) * DMODEL + c4);
        }
        __syncthreads();
        // per-row diag
#pragma unroll
        for (int rr = 0; rr < 8; ++rr) {
            int r = (w << 3) + rr;
            float x = k_s[r][lane];
            x = warpReduceSum(x * x);
            if (lane == 0) diag_s[r] = DIAG_C * x;
        }
        __syncthreads();
        // phase A: kdash -> E, track max
        {
            float dots[4][4];
#pragma unroll
            for (int i = 0; i < 4; ++i)
#pragma unroll
                for (int j = 0; j < 4; ++j) dots[i][j] = 0.f;
#pragma unroll
            for (int dd = 0; dd < 16; ++dd) {
                float4 kq[4], pp[4];
#pragma unroll
                for (int i = 0; i < 4; ++i) kq[i] = *(const float4*)&k_s[(rt << 2) + i][dd << 2];
#pragma unroll
                for (int j = 0; j < 4; ++j) pp[j] = *(const float4*)&proj_s[mt2 + (j << 5)][dd << 2];
#pragma unroll
                for (int i = 0; i < 4; ++i)
#pragma unroll
                    for (int j = 0; j < 4; ++j)
                        dots[i][j] += kq[i].x * pp[j].x + kq[i].y * pp[j].y +
                                      kq[i].z * pp[j].z + kq[i].w * pp[j].w;
            }
#pragma unroll
            for (int i = 0; i < 4; ++i) {
                const float dg = diag_s[(rt << 2) + i];
#pragma unroll
                for (int j = 0; j < 4; ++j) {
                    float kd = NORMALIZER * dots[i][j];
                    lmax = fmaxf(lmax, kd);
                    kp_s[(rt << 2) + i][mt2 + (j << 5)] = __expf(kd - dg);
                }
            }
        }
        __syncthreads();
        // phase B: accumulate context + esum
#pragma unroll
        for (int r = 0; r < 32; ++r) {
            float4 kv = *(const float4*)&kp_s[r][mloc];
            float4 va = *(const float4*)&v_s[r][e0];
            float4 vb = *(const float4*)&v_s[r][e0 + 4];
            float kvf[4] = {kv.x, kv.y, kv.z, kv.w};
            float vf[8]  = {va.x, va.y, va.z, va.w, vb.x, vb.y, vb.z, vb.w};
#pragma unroll
            for (int i = 0; i < 4; ++i)
#pragma unroll
                for (int j = 0; j < 8; ++j) acc[i][j] += kvf[i] * vf[j];
            if (eg == 0) {
#pragma unroll
                for (int i = 0; i < 4; ++i) esacc[i] += kvf[i];
            }
        }
        __syncthreads();
    }

    // flush
    float* cb = ctxp + ((size_t)(bh * MFEAT + m0 + mloc)) * DHEAD + e0;
#pragma unroll
    for (int i = 0; i < 4; ++i)
#pragma unroll
        for (int j = 0; j < 8; ++j)
            atomicAdd(cb + (size_t)i * DHEAD + j, acc[i][j]);
    if (eg == 0) {
#pragma unroll
        for (int i = 0; i < 4; ++i)
            atomicAdd(&esum[bh * MFEAT + m0 + mloc + i], esacc[i]);
    }
#pragma unroll
    for (int off = 32; off > 0; off >>= 1) lmax = fmaxf(lmax, __shfl_xor(lmax, off));
    if (lane == 0) wmax_s[w] = lmax;
    __syncthreads();
    if (tid == 0) {
        float mx = fmaxf(fmaxf(wmax_s[0], wmax_s[1]), fmaxf(wmax_s[2], wmax_s[3]));
        atomicMaxF(gmax, mx);
    }
}

// ---------------------------------------------------------------------------
// q-side: per row compute q'' = exp(qdash - diag - rowmax) + eps, then
// out[n,e] = sum_m (s*dinv*q''[m]) * ctxp[m,e] + (eps*qsum*dinv) * vsum[e]
// with denom = s*sum(q''*esum) + eps*N*sum(q'').  Grid (32, 256), block 256.
// ---------------------------------------------------------------------------
__global__ __launch_bounds__(256)
void qside_kernel(const float* __restrict__ Q, const float* __restrict__ projq,
                  const float* __restrict__ ctxp, const float* __restrict__ esum,
                  const float* __restrict__ vsum, const float* __restrict__ gmax,
                  float* __restrict__ ctx_out)
{
    __shared__ float proj_s[128][68];
    __shared__ float qd_s[16][516];
    __shared__ float q_s[16][64];
    __shared__ float diag_s[16];
    __shared__ float vterm_s[16];

    const int tid = threadIdx.x;
    const int bh = blockIdx.x;
    const int b = bh >> 3, h = bh & 7;
    const int n0 = blockIdx.y << 4;

    const float sG = __expf(-*gmax);
    const float* qbase = Q + ((size_t)b * NSEQ) * DMODEL + h * DHEAD;

    // stage 16 q rows
    {
        int row = tid >> 4;
        int c4 = (tid & 15) << 2;
        *(float4*)&q_s[row][c4] = *(const float4*)(qbase + (size_t)(n0 + row) * DMODEL + c4);
    }
    __syncthreads();
    const int w = tid >> 6, lane = tid & 63;
#pragma unroll
    for (int rr = 0; rr < 4; ++rr) {
        int r = (w << 2) + rr;
        float x = q_s[r][lane];
        x = warpReduceSum(x * x);
        if (lane == 0) diag_s[r] = DIAG_C * x;
    }

    const int rt = tid >> 5;      // 0..7
    const int mt2 = tid & 31;

    for (int mc = 0; mc < 4; ++mc) {
        __syncthreads();
#pragma unroll
        for (int t = 0; t < 8; ++t) {
            int lin = tid + (t << 8);
            int row = lin >> 4;
            int c4 = (lin & 15) << 2;
            *(float4*)&proj_s[row][c4] =
                *(const float4*)(projq + (size_t)((mc << 7) + row) * DHEAD + c4);
        }
        __syncthreads();
        float dots[2][4];
#pragma unroll
        for (int i = 0; i < 2; ++i)
#pragma unroll
            for (int j = 0; j < 4; ++j) dots[i][j] = 0.f;
#pragma unroll
        for (int dd = 0; dd < 16; ++dd) {
            float4 qq[2], pp[4];
#pragma unroll
            for (int i = 0; i < 2; ++i) qq[i] = *(const float4*)&q_s[(rt << 1) + i][dd << 2];
#pragma unroll
            for (int j = 0; j < 4; ++j) pp[j] = *(const float4*)&proj_s[mt2 + (j << 5)][dd << 2];
#pragma unroll
            for (int i = 0; i < 2; ++i)
#pragma unroll
                for (int j = 0; j < 4; ++j)
                    dots[i][j] += qq[i].x * pp[j].x + qq[i].y * pp[j].y +
                                  qq[i].z * pp[j].z + qq[i].w * pp[j].w;
        }
#pragma unroll
        for (int i = 0; i < 2; ++i)
#pragma unroll
            for (int j = 0; j < 4; ++j)
                qd_s[(rt << 1) + i][(mc << 7) + mt2 + (j << 5)] = NORMALIZER * dots[i][j];
    }
    __syncthreads();

    // phase 1b: rowmax, exp, prescale
    const float* esb = esum + bh * MFEAT;
#pragma unroll
    for (int rr = 0; rr < 4; ++rr) {
        int r = (w << 2) + rr;
        float vals[8];
        float rmax = -1e30f;
#pragma unroll
        for (int j = 0; j < 8; ++j) {
            vals[j] = qd_s[r][lane + (j << 6)];
            rmax = fmaxf(rmax, vals[j]);
        }
#pragma unroll
        for (int off = 32; off > 0; off >>= 1) rmax = fmaxf(rmax, __shfl_xor(rmax, off));
        const float dg = diag_s[r];
        float qsum = 0.f, de = 0.f;
#pragma unroll
        for (int j = 0; j < 8; ++j) {
            float e = __expf(vals[j] - dg - rmax) + KEPS;
            vals[j] = e;
            qsum += e;
            de += e * esb[lane + (j << 6)];
        }
        qsum = warpReduceSum(qsum);
        de = warpReduceSum(de);
        const float denom = sG * de + KEPS * 4096.0f * qsum;
        const float pres = sG / denom;
#pragma unroll
        for (int j = 0; j < 8; ++j) qd_s[r][lane + (j << 6)] = vals[j] * pres;
        if (lane == 0) vterm_s[r] = KEPS * qsum / denom;
    }
    __syncthreads();

    // phase 2: out = qd_s . ctxp + vterm*vsum
    {
        const int r = tid >> 4;
        const int e4 = (tid & 15) << 2;
        const float* cb = ctxp + ((size_t)bh * MFEAT) * DHEAD + e4;
        float a0 = 0.f, a1 = 0.f, a2 = 0.f, a3 = 0.f;
#pragma unroll 8
        for (int m = 0; m < MFEAT; ++m) {
            float qs = qd_s[r][m];
            float4 c = *(const float4*)(cb + (size_t)m * DHEAD);
            a0 += qs * c.x; a1 += qs * c.y; a2 += qs * c.z; a3 += qs * c.w;
        }
        const float4 vs = *(const float4*)(vsum + bh * DHEAD + e4);
        const float vt = vterm_s[r];
        float4 o;
        o.x = a0 + vt * vs.x;
        o.y = a1 + vt * vs.y;
        o.z = a2 + vt * vs.z;
        o.w = a3 + vt * vs.w;
        *(float4*)(ctx_out + ((size_t)b * NSEQ + n0 + r) * DMODEL + h * DHEAD + e4) = o;
    }
}

// ---------------------------------------------------------------------------
// LayerNorm over D=512, 1 wave per row. Grid 16384, block 64.
// ---------------------------------------------------------------------------
__global__ __launch_bounds__(64)
void ln_kernel(const float* __restrict__ hid, const float* __restrict__ gamma,
               const float* __restrict__ beta, float* __restrict__ out)
{
    const int row = blockIdx.x;
    const int lane = threadIdx.x;
    const float* x = hid + (size_t)row * DMODEL + (lane << 3);
    float4 a = *(const float4*)x;
    float4 c = *(const float4*)(x + 4);
    float s = a.x + a.y + a.z + a.w + c.x + c.y + c.z + c.w;
    float sq = a.x * a.x + a.y * a.y + a.z * a.z + a.w * a.w +
               c.x * c.x + c.y * c.y + c.z * c.z + c.w * c.w;
    s = warpReduceSum(s);
    sq = warpReduceSum(sq);
    const float mu = s * 0.001953125f;
    const float var = sq * 0.001953125f - mu * mu;
    const float rs = rsqrtf(var + 1e-12f);
    const float4 g1 = *(const float4*)(gamma + (lane << 3));
    const float4 g2 = *(const float4*)(gamma + (lane << 3) + 4);
    const float4 b1 = *(const float4*)(beta + (lane << 3));
    const float4 b2 = *(const float4*)(beta + (lane << 3) + 4);
    float4 o1, o2;
    o1.x = (a.x - mu) * rs * g1.x + b1.x;
    o1.y = (a.y - mu) * rs * g1.y + b1.y;
    o1.z = (a.z - mu) * rs * g1.z + b1.z;
    o1.w = (a.w - mu) * rs * g1.w + b1.w;
    o2.x = (c.x - mu) * rs * g2.x + b2.x;
    o2.y = (c.y - mu) * rs * g2.y + b2.y;
    o2.z = (c.z - mu) * rs * g2.z + b2.z;
    o2.w = (c.w - mu) * rs * g2.w + b2.w;
    *(float4*)(out + (size_t)row * DMODEL + (lane << 3)) = o1;
    *(float4*)(out + (size_t)row * DMODEL + (lane << 3) + 4) = o2;
}

__global__ void init_misc(float* gmax)
{
    if (threadIdx.x == 0 && blockIdx.x == 0) *gmax = -1e30f;
}

// ---------------------------------------------------------------------------
extern "C" void kernel_launch(void* const* d_in, const int* in_sizes, int n_in,
                              void* d_out, int out_size, void* d_ws, size_t ws_size,
                              hipStream_t stream)
{
    const float* x     = (const float*)d_in[0];
    // d_in[1] attention_mask: unused by the reference module
    const float* Wq    = (const float*)d_in[2];
    const float* bq    = (const float*)d_in[3];
    const float* Wk    = (const float*)d_in[4];
    const float* bk    = (const float*)d_in[5];
    const float* Wv    = (const float*)d_in[6];
    const float* bv    = (const float*)d_in[7];
    const float* projq = (const float*)d_in[8];
    const float* projk = (const float*)d_in[9];
    const float* Wd    = (const float*)d_in[10];
    const float* bd    = (const float*)d_in[11];
    const float* gamma = (const float*)d_in[12];
    const float* beta  = (const float*)d_in[13];

    float* ws = (float*)d_ws;
    const size_t SZ = (size_t)ROWS_TOTAL * DMODEL;      // 8388608 floats
    float* qb    = ws;                                  // q,  later free
    float* kb    = ws + SZ;                             // k,  later hidden
    float* vb    = ws + 2 * SZ;                         // v,  later ctx_out
    float* ctxp  = ws + 3 * SZ;                         // [32][512][64]
    float* esumb = ctxp + (size_t)BHEADS * MFEAT * DHEAD;
    float* vsumb = esumb + BHEADS * MFEAT;
    float* gmaxb = vsumb + BHEADS * DHEAD;
    // total ws use ~100 MiB

    hipMemsetAsync(ctxp, 0,
                   ((size_t)BHEADS * MFEAT * DHEAD + BHEADS * MFEAT + BHEADS * DHEAD) * sizeof(float),
                   stream);
    init_misc<<<1, 64, 0, stream>>>(gmaxb);

    dim3 ggrid(8, 256);
    gemm_bt<<<ggrid, 256, 0, stream>>>(x, Wq, bq, nullptr, qb);
    gemm_bt<<<ggrid, 256, 0, stream>>>(x, Wk, bk, nullptr, kb);
    gemm_bt<<<ggrid, 256, 0, stream>>>(x, Wv, bv, nullptr, vb);

    vsum_kernel<<<dim3(32, 16), 64, 0, stream>>>(vb, vsumb);
    kside_kernel<<<dim3(32, 4, 8), 256, 0, stream>>>(kb, vb, projk, ctxp, esumb, gmaxb);
    qside_kernel<<<dim3(32, 256), 256, 0, stream>>>(qb, projq, ctxp, esumb, vsumb, gmaxb, vb);

    // hidden = ctx @ Wd^T + bd + x  -> kb
    gemm_bt<<<ggrid, 256, 0, stream>>>(vb, Wd, bd, x, kb);
    ln_kernel<<<16384, 64, 0, stream>>>(kb, gamma, beta, (float*)d_out);
}

// Round 2
// 696.480 us; speedup vs baseline: 2.6638x; 2.6638x over previous
//
#include <hip/hip_runtime.h>
#include <math.h>

typedef __bf16 bf16;
typedef __bf16 bf16x8 __attribute__((ext_vector_type(8)));
typedef float  f32x4  __attribute__((ext_vector_type(4)));

#define NSEQ 4096
#define DMODEL 512
#define DHEAD 64
#define MFEAT 512
#define BHEADS 32
#define ROWS_TOTAL 16384

#define NORMALIZER 0.35355339059327373f
#define DIAG_C 0.0625f
#define KEPS 1e-4f

__device__ __forceinline__ float warpReduceSum(float v) {
#pragma unroll
    for (int off = 32; off > 0; off >>= 1) v += __shfl_xor(v, off);
    return v;
}

__device__ __forceinline__ void atomicMaxF(float* addr, float val) {
    int* ai = (int*)addr;
    int cur = __float_as_int(*addr);
    while (__int_as_float(cur) < val) {
        int prev = atomicCAS(ai, cur, __float_as_int(val));
        if (prev == cur) break;
        cur = prev;
    }
}

__device__ __forceinline__ void gload16(const void* g, void* l) {
    __builtin_amdgcn_global_load_lds((const __attribute__((address_space(1))) void*)g,
                                     (__attribute__((address_space(3))) void*)l, 16, 0, 0);
}

// ---------------------------------------------------------------------------
// prep: f32 -> bf16 conversions + weight concat + bias concat
// ---------------------------------------------------------------------------
__global__ __launch_bounds__(256)
void prep_convert(const float* __restrict__ x, const float* __restrict__ Wq,
                  const float* __restrict__ Wk, const float* __restrict__ Wv,
                  const float* __restrict__ Wd, const float* __restrict__ pq,
                  const float* __restrict__ bq, const float* __restrict__ bk,
                  const float* __restrict__ bv,
                  bf16* __restrict__ xb, bf16* __restrict__ Wb,
                  bf16* __restrict__ Wdb, bf16* __restrict__ pqb,
                  float* __restrict__ bcat)
{
    size_t i4 = (size_t)blockIdx.x * 256 + threadIdx.x;
    size_t e0 = i4 * 4;
    if (e0 >= 9471488) return;
    const float* src;
    if (e0 < 8388608) {
        src = x + e0;
        float4 v = *(const float4*)src;
        bf16* d = xb + e0;
        d[0] = (bf16)v.x; d[1] = (bf16)v.y; d[2] = (bf16)v.z; d[3] = (bf16)v.w;
    } else if (e0 < 9175040) {
        size_t c = e0 - 8388608; int wsel = (int)(c >> 18); size_t o = c & 262143;
        src = (wsel == 0 ? Wq : wsel == 1 ? Wk : Wv) + o;
        float4 v = *(const float4*)src;
        bf16* d = Wb + c;
        d[0] = (bf16)v.x; d[1] = (bf16)v.y; d[2] = (bf16)v.z; d[3] = (bf16)v.w;
    } else if (e0 < 9437184) {
        size_t c = e0 - 9175040;
        src = Wd + c;
        float4 v = *(const float4*)src;
        bf16* d = Wdb + c;
        d[0] = (bf16)v.x; d[1] = (bf16)v.y; d[2] = (bf16)v.z; d[3] = (bf16)v.w;
    } else if (e0 < 9469952) {
        size_t c = e0 - 9437184;
        src = pq + c;
        float4 v = *(const float4*)src;
        bf16* d = pqb + c;
        d[0] = (bf16)v.x; d[1] = (bf16)v.y; d[2] = (bf16)v.z; d[3] = (bf16)v.w;
    } else {
        size_t c = e0 - 9469952; int wsel = (int)(c >> 9); size_t o = c & 511;
        src = (wsel == 0 ? bq : wsel == 1 ? bk : bv) + o;
        *(float4*)(bcat + c) = *(const float4*)src;
    }
}

// ---------------------------------------------------------------------------
// bf16 MFMA GEMM, C = A * B^T (+bias)(+resid), 128x128 tile, BK=64.
// MODE 0: A=xb16 [16384x512], B=Wcat [1536x512]; writes q(bf16)/k(f32)/v(f32)
// MODE 1: A=ctxb16 [16384x512], B=Wd [512x512]; out f32 = +bias +resid
// ---------------------------------------------------------------------------
template<int MODE>
__global__ __launch_bounds__(256)
void gemm_mfma(const bf16* __restrict__ A, const bf16* __restrict__ Bw,
               const float* __restrict__ bias, const float* __restrict__ resid,
               bf16* __restrict__ outQ, float* __restrict__ outK,
               float* __restrict__ outV, float* __restrict__ outF)
{
    __shared__ char As[16384];
    __shared__ char Bs[16384];
    const int tid = threadIdx.x;
    const int w = tid >> 6, l = tid & 63;
    const int wr = w >> 1, wc = w & 1;
    const int row0 = blockIdx.y << 7;
    const int col0 = blockIdx.x << 7;

    f32x4 acc[4][4] = {};
    const char* Ab = (const char*)A + (size_t)row0 * 1024;
    const char* Bb = (const char*)Bw + (size_t)col0 * 1024;

    for (int kt = 0; kt < 8; ++kt) {
        const int k0b = kt << 7;
#pragma unroll
        for (int i = 0; i < 4; ++i) {
            int off = (i << 12) + (tid << 4);
            int g = off ^ ((off >> 3) & 0x70);
            int grow = g >> 7, gcol = g & 127;
            gload16(Ab + (size_t)grow * 1024 + k0b + gcol, As + (i << 12) + (w << 10));
            gload16(Bb + (size_t)grow * 1024 + k0b + gcol, Bs + (i << 12) + (w << 10));
        }
        __syncthreads();
#pragma unroll
        for (int ks = 0; ks < 2; ++ks) {
            bf16x8 af[4], bb[4];
#pragma unroll
            for (int mi = 0; mi < 4; ++mi) {
                int row = (wr << 6) + (mi << 4) + (l & 15);
                int addr = ((row << 7) + (ks << 6) + ((l >> 4) << 4)) ^ ((row & 7) << 4);
                af[mi] = *(const bf16x8*)(As + addr);
            }
#pragma unroll
            for (int nj = 0; nj < 4; ++nj) {
                int row = (wc << 6) + (nj << 4) + (l & 15);
                int addr = ((row << 7) + (ks << 6) + ((l >> 4) << 4)) ^ ((row & 7) << 4);
                bb[nj] = *(const bf16x8*)(Bs + addr);
            }
#pragma unroll
            for (int mi = 0; mi < 4; ++mi)
#pragma unroll
                for (int nj = 0; nj < 4; ++nj)
                    acc[mi][nj] = __builtin_amdgcn_mfma_f32_16x16x32_bf16(af[mi], bb[nj], acc[mi][nj], 0, 0, 0);
        }
        __syncthreads();
    }

    const int subrow = (l >> 4) << 2;
    const int subcol = l & 15;
#pragma unroll
    for (int mi = 0; mi < 4; ++mi) {
#pragma unroll
        for (int nj = 0; nj < 4; ++nj) {
            const int cg = col0 + (wc << 6) + (nj << 4) + subcol;
            const float bi = bias[cg];
#pragma unroll
            for (int r = 0; r < 4; ++r) {
                const int rg = row0 + (wr << 6) + (mi << 4) + subrow + r;
                float v = acc[mi][nj][r] + bi;
                if (MODE == 0) {
                    if (cg < 512)       outQ[(size_t)rg * 512 + cg] = (bf16)v;
                    else if (cg < 1024) outK[(size_t)rg * 512 + (cg - 512)] = v;
                    else                outV[(size_t)rg * 512 + (cg - 1024)] = v;
                } else {
                    v += resid[(size_t)rg * 512 + cg];
                    outF[(size_t)rg * 512 + cg] = v;
                }
            }
        }
    }
}

// ---------------------------------------------------------------------------
// vsum[bh,e] = sum_n V[b,n,h*64+e]. Grid (32,16), block 64.
// ---------------------------------------------------------------------------
__global__ __launch_bounds__(64)
void vsum_kernel(const float* __restrict__ V, float* __restrict__ vsum)
{
    const int bh = blockIdx.x;
    const int b = bh >> 3, h = bh & 7;
    const int e = threadIdx.x;
    const int n0 = blockIdx.y << 8;
    const float* base = V + ((size_t)b * NSEQ + n0) * DMODEL + h * DHEAD + e;
    float s = 0.f;
    for (int n = 0; n < 256; ++n) s += base[(size_t)n * DMODEL];
    atomicAdd(&vsum[bh * DHEAD + e], s);
}

// ---------------------------------------------------------------------------
// k-side (f32, unchanged from round 1): ctx_pure, esum, gmax
// ---------------------------------------------------------------------------
__global__ __launch_bounds__(256)
void kside_kernel(const float* __restrict__ K, const float* __restrict__ V,
                  const float* __restrict__ projk,
                  float* __restrict__ ctxp, float* __restrict__ esum,
                  float* __restrict__ gmax)
{
    __shared__ float proj_s[128][68];
    __shared__ float k_s[32][64];
    __shared__ float v_s[32][64];
    __shared__ float kp_s[32][128];
    __shared__ float diag_s[32];
    __shared__ float wmax_s[4];

    const int tid = threadIdx.x;
    const int bh = blockIdx.x;
    const int b = bh >> 3, h = bh & 7;
    const int m0 = blockIdx.y << 7;
    const int n0 = blockIdx.z << 9;

#pragma unroll
    for (int t = 0; t < 8; ++t) {
        int lin = tid + (t << 8);
        int row = lin >> 4;
        int c4 = (lin & 15) << 2;
        *(float4*)&proj_s[row][c4] =
            *(const float4*)(projk + (size_t)(m0 + row) * DHEAD + c4);
    }

    const float* kbase = K + ((size_t)b * NSEQ) * DMODEL + h * DHEAD;
    const float* vbase = V + ((size_t)b * NSEQ) * DMODEL + h * DHEAD;

    float acc[4][8];
#pragma unroll
    for (int i = 0; i < 4; ++i)
#pragma unroll
        for (int j = 0; j < 8; ++j) acc[i][j] = 0.f;
    float esacc[4] = {0.f, 0.f, 0.f, 0.f};
    float lmax = -1e30f;

    const int eg = tid & 7;
    const int mg = tid >> 3;
    const int e0 = eg << 3;
    const int mloc = mg << 2;
    const int rt = tid >> 5;
    const int mt2 = tid & 31;
    const int w = tid >> 6, lane = tid & 63;

    __syncthreads();

    for (int it = 0; it < 16; ++it) {
        const int nb = n0 + (it << 5);
#pragma unroll
        for (int t = 0; t < 2; ++t) {
            int lin = tid + (t << 8);
            int row = lin >> 4;
            int c4 = (lin & 15) << 2;
            *(float4*)&k_s[row][c4] = *(const float4*)(kbase + (size_t)(nb + row) * DMODEL + c4);
            *(float4*)&v_s[row][c4] = *(const float4*)(vbase + (size_t)(nb + row) * DMODEL + c4);
        }
        __syncthreads();
#pragma unroll
        for (int rr = 0; rr < 8; ++rr) {
            int r = (w << 3) + rr;
            float x = k_s[r][lane];
            x = warpReduceSum(x * x);
            if (lane == 0) diag_s[r] = DIAG_C * x;
        }
        __syncthreads();
        {
            float dots[4][4];
#pragma unroll
            for (int i = 0; i < 4; ++i)
#pragma unroll
                for (int j = 0; j < 4; ++j) dots[i][j] = 0.f;
#pragma unroll
            for (int dd = 0; dd < 16; ++dd) {
                float4 kq[4], pp[4];
#pragma unroll
                for (int i = 0; i < 4; ++i) kq[i] = *(const float4*)&k_s[(rt << 2) + i][dd << 2];
#pragma unroll
                for (int j = 0; j < 4; ++j) pp[j] = *(const float4*)&proj_s[mt2 + (j << 5)][dd << 2];
#pragma unroll
                for (int i = 0; i < 4; ++i)
#pragma unroll
                    for (int j = 0; j < 4; ++j)
                        dots[i][j] += kq[i].x * pp[j].x + kq[i].y * pp[j].y +
                                      kq[i].z * pp[j].z + kq[i].w * pp[j].w;
            }
#pragma unroll
            for (int i = 0; i < 4; ++i) {
                const float dg = diag_s[(rt << 2) + i];
#pragma unroll
                for (int j = 0; j < 4; ++j) {
                    float kd = NORMALIZER * dots[i][j];
                    lmax = fmaxf(lmax, kd);
                    kp_s[(rt << 2) + i][mt2 + (j << 5)] = __expf(kd - dg);
                }
            }
        }
        __syncthreads();
#pragma unroll
        for (int r = 0; r < 32; ++r) {
            float4 kv = *(const float4*)&kp_s[r][mloc];
            float4 va = *(const float4*)&v_s[r][e0];
            float4 vb = *(const float4*)&v_s[r][e0 + 4];
            float kvf[4] = {kv.x, kv.y, kv.z, kv.w};
            float vf[8]  = {va.x, va.y, va.z, va.w, vb.x, vb.y, vb.z, vb.w};
#pragma unroll
            for (int i = 0; i < 4; ++i)
#pragma unroll
                for (int j = 0; j < 8; ++j) acc[i][j] += kvf[i] * vf[j];
            if (eg == 0) {
#pragma unroll
                for (int i = 0; i < 4; ++i) esacc[i] += kvf[i];
            }
        }
        __syncthreads();
    }

    float* cb = ctxp + ((size_t)(bh * MFEAT + m0 + mloc)) * DHEAD + e0;
#pragma unroll
    for (int i = 0; i < 4; ++i)
#pragma unroll
        for (int j = 0; j < 8; ++j)
            atomicAdd(cb + (size_t)i * DHEAD + j, acc[i][j]);
    if (eg == 0) {
#pragma unroll
        for (int i = 0; i < 4; ++i)
            atomicAdd(&esum[bh * MFEAT + m0 + mloc + i], esacc[i]);
    }
#pragma unroll
    for (int off = 32; off > 0; off >>= 1) lmax = fmaxf(lmax, __shfl_xor(lmax, off));
    if (lane == 0) wmax_s[w] = lmax;
    __syncthreads();
    if (tid == 0) {
        float mx = fmaxf(fmaxf(wmax_s[0], wmax_s[1]), fmaxf(wmax_s[2], wmax_s[3]));
        atomicMaxF(gmax, mx);
    }
}

// ---------------------------------------------------------------------------
// prep2: ctxp [bh][m][e] f32 -> ctxbT [bh][e][m] bf16; ctxsum[bh][e]; esumsum
// ---------------------------------------------------------------------------
__global__ __launch_bounds__(256)
void prep2_kernel(const float* __restrict__ ctxp, const float* __restrict__ esum,
                  bf16* __restrict__ ctxbT, float* __restrict__ ctxsum,
                  float* __restrict__ esumsum)
{
    __shared__ float cs_s[64][4];
    __shared__ float er_s[4];
    const int bh = blockIdx.x;
    const int tid = threadIdx.x;
    const int e = tid & 63, mq = tid >> 6;
    const float* cb = ctxp + (size_t)bh * MFEAT * DHEAD;
    bf16* ob = ctxbT + ((size_t)bh * 64 + e) * 512;
    float s = 0.f;
    for (int i = 0; i < 128; ++i) {
        int m = (mq << 7) + i;
        float v = cb[(size_t)m * 64 + e];
        s += v;
        ob[m] = (bf16)v;
    }
    cs_s[e][mq] = s;
    float p = esum[bh * 512 + tid] + esum[bh * 512 + 256 + tid];
    p = warpReduceSum(p);
    if ((tid & 63) == 0) er_s[tid >> 6] = p;
    __syncthreads();
    if (tid < 64)
        ctxsum[bh * 64 + tid] = cs_s[tid][0] + cs_s[tid][1] + cs_s[tid][2] + cs_s[tid][3];
    if (tid == 0) esumsum[bh] = er_s[0] + er_s[1] + er_s[2] + er_s[3];
}

// ---------------------------------------------------------------------------
// q-side MFMA: phase1 qdash = q*projq^T (K=64); T=exp(.-diag);
// phase2 U += T * ctxbT^T (K=512 over 4 feature tiles); epilogue scalars.
// Grid (32 bh, 32 ntiles), block 256 (4 waves, 2x2).
// ---------------------------------------------------------------------------
__global__ __launch_bounds__(256)
void qside_mfma(const bf16* __restrict__ Qb, const bf16* __restrict__ Pq,
                const bf16* __restrict__ CtxT, const float* __restrict__ esum,
                const float* __restrict__ vsum, const float* __restrict__ ctxsum,
                const float* __restrict__ esumsum, const float* __restrict__ gmax,
                bf16* __restrict__ OutC)
{
    __shared__ char q_s[16384];
    __shared__ char pq_s[16384];
    __shared__ char T_s[128 * 272];
    __shared__ float esum_s[512];
    __shared__ float vsum_s[64];
    __shared__ float ctxsum_s[64];
    __shared__ float diag_s[128];
    __shared__ int   tmax_s[128];
    __shared__ float red_s[256];
    __shared__ float red2_s[256];
    __shared__ float alpha_s[128], g1_s[128], g2_s[128];

    const int tid = threadIdx.x;
    const int w = tid >> 6, l = tid & 63;
    const int wr = w >> 1, wc = w & 1;
    const int bh = blockIdx.x;
    const int b = bh >> 3, h = bh & 7;
    const int n0 = blockIdx.y << 7;

    const char* qg = (const char*)Qb + (((size_t)(b * NSEQ + n0)) * DMODEL + h * DHEAD) * 2;
#pragma unroll
    for (int i = 0; i < 4; ++i) {
        int off = (i << 12) + (tid << 4);
        int g = off ^ ((off >> 3) & 0x70);
        gload16(qg + (size_t)(g >> 7) * 1024 + (g & 127), q_s + (i << 12) + (w << 10));
    }
    if (tid < 64) { vsum_s[tid] = vsum[bh * 64 + tid]; ctxsum_s[tid] = ctxsum[bh * 64 + tid]; }
    esum_s[tid] = esum[bh * 512 + tid];
    esum_s[tid + 256] = esum[bh * 512 + 256 + tid];
    if (tid < 128) tmax_s[tid] = 0;
    __syncthreads();

    // diag from staged q (swizzled reads)
    {
        const int row = tid >> 1, seg = tid & 1;
        float ss = 0.f;
#pragma unroll
        for (int j = 0; j < 4; ++j) {
            int addr = ((row << 7) + (((seg << 2) + j) << 4)) ^ ((row & 7) << 4);
            bf16x8 v = *(const bf16x8*)(q_s + addr);
#pragma unroll
            for (int u = 0; u < 8; ++u) { float f = (float)v[u]; ss += f * f; }
        }
        red_s[tid] = ss;
    }
    __syncthreads();
    if (tid < 128) diag_s[tid] = DIAG_C * (red_s[2 * tid] + red_s[2 * tid + 1]);
    __syncthreads();

    f32x4 acc2[4][2] = {};
    float uT = 0.f, uE = 0.f;
    const char* ctxg = (const char*)CtxT + (size_t)bh * 64 * 512 * 2;

    for (int ft = 0; ft < 4; ++ft) {
        const char* pg = (const char*)Pq + (size_t)ft * 128 * 128;
#pragma unroll
        for (int i = 0; i < 4; ++i) {
            int off = (i << 12) + (tid << 4);
            int g = off ^ ((off >> 3) & 0x70);
            gload16(pg + g, pq_s + (i << 12) + (w << 10));
        }
        __syncthreads();

        // phase 1: qdash tile [128 rows x 128 feats]
        f32x4 acc1[4][4] = {};
#pragma unroll
        for (int ks = 0; ks < 2; ++ks) {
            bf16x8 af[4], bb[4];
#pragma unroll
            for (int mi = 0; mi < 4; ++mi) {
                int row = (wr << 6) + (mi << 4) + (l & 15);
                int addr = ((row << 7) + (ks << 6) + ((l >> 4) << 4)) ^ ((row & 7) << 4);
                af[mi] = *(const bf16x8*)(q_s + addr);
            }
#pragma unroll
            for (int nj = 0; nj < 4; ++nj) {
                int fr = (wc << 6) + (nj << 4) + (l & 15);
                int addr = ((fr << 7) + (ks << 6) + ((l >> 4) << 4)) ^ ((fr & 7) << 4);
                bb[nj] = *(const bf16x8*)(pq_s + addr);
            }
#pragma unroll
            for (int mi = 0; mi < 4; ++mi)
#pragma unroll
                for (int nj = 0; nj < 4; ++nj)
                    acc1[mi][nj] = __builtin_amdgcn_mfma_f32_16x16x32_bf16(af[mi], bb[nj], acc1[mi][nj], 0, 0, 0);
        }

        // transform: T = exp(norm*qdash - diag) -> T_s bf16; track row Tmax
#pragma unroll
        for (int mi = 0; mi < 4; ++mi) {
#pragma unroll
            for (int r = 0; r < 4; ++r) {
                const int row = (wr << 6) + (mi << 4) + ((l >> 4) << 2) + r;
                const float dg = diag_s[row];
                float tmx = 0.f;
#pragma unroll
                for (int nj = 0; nj < 4; ++nj) {
                    int m = (wc << 6) + (nj << 4) + (l & 15);
                    float t = __expf(NORMALIZER * acc1[mi][nj][r] - dg);
                    tmx = fmaxf(tmx, t);
                    *(bf16*)(T_s + row * 272 + m * 2) = (bf16)t;
                }
#pragma unroll
                for (int m2 = 1; m2 < 16; m2 <<= 1) tmx = fmaxf(tmx, __shfl_xor(tmx, m2));
                if ((l & 15) == 0) atomicMax(&tmax_s[row], __float_as_int(tmx));
            }
        }
        __syncthreads();

        // phase 2: acc2 += T_s * ctxbT (K=128 this tile)
        {
            bf16x8 bfr[4][2];
#pragma unroll
            for (int ks = 0; ks < 4; ++ks)
#pragma unroll
                for (int nj = 0; nj < 2; ++nj) {
                    int e = (wc << 5) + (nj << 4) + (l & 15);
                    size_t go = (((size_t)e * 512) + (ft << 7) + (ks << 5) + ((l >> 4) << 3)) * 2;
                    bfr[ks][nj] = *(const bf16x8*)(ctxg + go);
                }
#pragma unroll
            for (int ks = 0; ks < 4; ++ks) {
                bf16x8 af[4];
#pragma unroll
                for (int mi = 0; mi < 4; ++mi) {
                    int row = (wr << 6) + (mi << 4) + (l & 15);
                    af[mi] = *(const bf16x8*)(T_s + row * 272 + (ks << 6) + ((l >> 4) << 4));
                }
#pragma unroll
                for (int mi = 0; mi < 4; ++mi)
#pragma unroll
                    for (int nj = 0; nj < 2; ++nj)
                        acc2[mi][nj] = __builtin_amdgcn_mfma_f32_16x16x32_bf16(af[mi], bfr[ks][nj], acc2[mi][nj], 0, 0, 0);
            }
        }

        // uT / uE accumulation for this feature tile
        {
            const int row = tid >> 1, seg = tid & 1;
            const float* es = esum_s + (ft << 7) + (seg << 6);
            const char* tb = T_s + row * 272 + (seg << 7);
#pragma unroll
            for (int c8 = 0; c8 < 8; ++c8) {
                bf16x8 v = *(const bf16x8*)(tb + (c8 << 4));
#pragma unroll
                for (int u = 0; u < 8; ++u) {
                    float f = (float)v[u];
                    uT += f;
                    uE += f * es[(c8 << 3) + u];
                }
            }
        }
    }
    __syncthreads();

    red_s[tid] = uT; red2_s[tid] = uE;
    __syncthreads();
    if (tid < 128) {
        const float sG = __expf(-gmax[0]);
        const float ess = esumsum[bh];
        float uTr = red_s[2 * tid] + red_s[2 * tid + 1];
        float uEr = red2_s[2 * tid] + red2_s[2 * tid + 1];
        float tmax = __int_as_float(tmax_s[tid]);
        float cr = __expf(-diag_s[tid]) / tmax;
        float qsum = cr * uTr + KEPS * 512.0f;
        float denom = sG * (cr * uEr + KEPS * ess) + KEPS * 4096.0f * qsum;
        float inv = 1.0f / denom;
        alpha_s[tid] = sG * cr * inv;
        g1_s[tid] = sG * KEPS * inv;
        g2_s[tid] = KEPS * qsum * inv;
    }
    __syncthreads();

    bf16* outbase = OutC + ((size_t)(b * NSEQ + n0)) * DMODEL + h * DHEAD;
#pragma unroll
    for (int mi = 0; mi < 4; ++mi)
#pragma unroll
        for (int r = 0; r < 4; ++r) {
            const int row = (wr << 6) + (mi << 4) + ((l >> 4) << 2) + r;
            const float al = alpha_s[row], G1 = g1_s[row], G2 = g2_s[row];
#pragma unroll
            for (int nj = 0; nj < 2; ++nj) {
                int e = (wc << 5) + (nj << 4) + (l & 15);
                float v = al * acc2[mi][nj][r] + G1 * ctxsum_s[e] + G2 * vsum_s[e];
                outbase[(size_t)row * DMODEL + e] = (bf16)v;
            }
        }
}

// ---------------------------------------------------------------------------
// LayerNorm over D=512, 1 wave per row.
// ---------------------------------------------------------------------------
__global__ __launch_bounds__(64)
void ln_kernel(const float* __restrict__ hid, const float* __restrict__ gamma,
               const float* __restrict__ beta, float* __restrict__ out)
{
    const int row = blockIdx.x;
    const int lane = threadIdx.x;
    const float* x = hid + (size_t)row * DMODEL + (lane << 3);
    float4 a = *(const float4*)x;
    float4 c = *(const float4*)(x + 4);
    float s = a.x + a.y + a.z + a.w + c.x + c.y + c.z + c.w;
    float sq = a.x * a.x + a.y * a.y + a.z * a.z + a.w * a.w +
               c.x * c.x + c.y * c.y + c.z * c.z + c.w * c.w;
    s = warpReduceSum(s);
    sq = warpReduceSum(sq);
    const float mu = s * 0.001953125f;
    const float var = sq * 0.001953125f - mu * mu;
    const float rs = rsqrtf(var + 1e-12f);
    const float4 g1 = *(const float4*)(gamma + (lane << 3));
    const float4 g2 = *(const float4*)(gamma + (lane << 3) + 4);
    const float4 b1 = *(const float4*)(beta + (lane << 3));
    const float4 b2 = *(const float4*)(beta + (lane << 3) + 4);
    float4 o1, o2;
    o1.x = (a.x - mu) * rs * g1.x + b1.x;
    o1.y = (a.y - mu) * rs * g1.y + b1.y;
    o1.z = (a.z - mu) * rs * g1.z + b1.z;
    o1.w = (a.w - mu) * rs * g1.w + b1.w;
    o2.x = (c.x - mu) * rs * g2.x + b2.x;
    o2.y = (c.y - mu) * rs * g2.y + b2.y;
    o2.z = (c.z - mu) * rs * g2.z + b2.z;
    o2.w = (c.w - mu) * rs * g2.w + b2.w;
    *(float4*)(out + (size_t)row * DMODEL + (lane << 3)) = o1;
    *(float4*)(out + (size_t)row * DMODEL + (lane << 3) + 4) = o2;
}

__global__ void init_misc(float* gmax)
{
    if (threadIdx.x == 0 && blockIdx.x == 0) *gmax = -1e30f;
}

// ---------------------------------------------------------------------------
extern "C" void kernel_launch(void* const* d_in, const int* in_sizes, int n_in,
                              void* d_out, int out_size, void* d_ws, size_t ws_size,
                              hipStream_t stream)
{
    const float* x     = (const float*)d_in[0];
    const float* Wq    = (const float*)d_in[2];
    const float* bq    = (const float*)d_in[3];
    const float* Wk    = (const float*)d_in[4];
    const float* bk    = (const float*)d_in[5];
    const float* Wv    = (const float*)d_in[6];
    const float* bv    = (const float*)d_in[7];
    const float* projq = (const float*)d_in[8];
    const float* projk = (const float*)d_in[9];
    const float* Wd    = (const float*)d_in[10];
    const float* bd    = (const float*)d_in[11];
    const float* gamma = (const float*)d_in[12];
    const float* beta  = (const float*)d_in[13];

    char* W = (char*)d_ws;
    bf16*  qb16   = (bf16*) (W);                  // 16,777,216 B
    float* kf32   = (float*)(W + 16777216);       // 33,554,432 B (reused as hidden)
    float* vf32   = (float*)(W + 50331648);       // 33,554,432 B
    bf16*  xb16   = (bf16*) (W + 83886080);       // 16,777,216 B (reused as ctx bf16)
    bf16*  Wb16   = (bf16*) (W + 100663296);      // 1,572,864 B
    bf16*  Wdb16  = (bf16*) (W + 102236160);      // 524,288 B
    bf16*  pqb16  = (bf16*) (W + 102760448);      // 65,536 B
    float* bcat   = (float*)(W + 102825984);      // 6,144 B
    float* ctxp   = (float*)(W + 102832128);      // 4,194,304 B
    float* esumb  = (float*)(W + 107026432);      // 65,536 B
    float* vsumb  = (float*)(W + 107091968);      // 8,192 B
    bf16*  ctxbT  = (bf16*) (W + 107100160);      // 2,097,152 B
    float* ctxsum = (float*)(W + 109197312);      // 8,192 B
    float* esmsm  = (float*)(W + 109205504);      // 128 B
    float* gmaxb  = (float*)(W + 109205632);      // 4 B

    prep_convert<<<9250, 256, 0, stream>>>(x, Wq, Wk, Wv, Wd, projq, bq, bk, bv,
                                           xb16, Wb16, Wdb16, pqb16, bcat);

    hipMemsetAsync(ctxp, 0, 4194304 + 65536 + 8192, stream);
    init_misc<<<1, 64, 0, stream>>>(gmaxb);

    gemm_mfma<0><<<dim3(12, 128), 256, 0, stream>>>(xb16, Wb16, bcat, nullptr,
                                                    qb16, kf32, vf32, nullptr);

    vsum_kernel<<<dim3(32, 16), 64, 0, stream>>>(vf32, vsumb);
    kside_kernel<<<dim3(32, 4, 8), 256, 0, stream>>>(kf32, vf32, projk, ctxp, esumb, gmaxb);
    prep2_kernel<<<32, 256, 0, stream>>>(ctxp, esumb, ctxbT, ctxsum, esmsm);

    qside_mfma<<<dim3(32, 32), 256, 0, stream>>>(qb16, pqb16, ctxbT, esumb, vsumb,
                                                 ctxsum, esmsm, gmaxb, xb16);

    gemm_mfma<1><<<dim3(4, 128), 256, 0, stream>>>(xb16, Wdb16, bd, x,
                                                   nullptr, nullptr, nullptr, kf32);
    ln_kernel<<<16384, 64, 0, stream>>>(kf32, gamma, beta, (float*)d_out);
}

// Round 3
// 270.295 us; speedup vs baseline: 6.8640x; 2.5767x over previous
//
#include <hip/hip_runtime.h>
#include <math.h>

typedef __bf16 bf16;
typedef __bf16 bf16x8 __attribute__((ext_vector_type(8)));
typedef __bf16 bf16x4 __attribute__((ext_vector_type(4)));
typedef float  f32x4  __attribute__((ext_vector_type(4)));

#define NSEQ 4096
#define DMODEL 512
#define DHEAD 64
#define MFEAT 512
#define BHEADS 32
#define ROWS_TOTAL 16384

#define NORMALIZER 0.35355339059327373f
#define DIAG_C 0.0625f
#define KEPS 1e-4f

__device__ __forceinline__ float warpReduceSum(float v) {
#pragma unroll
    for (int off = 32; off > 0; off >>= 1) v += __shfl_xor(v, off);
    return v;
}

__device__ __forceinline__ void atomicMaxF(float* addr, float val) {
    int* ai = (int*)addr;
    int cur = __float_as_int(*addr);
    while (__int_as_float(cur) < val) {
        int prev = atomicCAS(ai, cur, __float_as_int(val));
        if (prev == cur) break;
        cur = prev;
    }
}

__device__ __forceinline__ void gload16(const void* g, void* l) {
    __builtin_amdgcn_global_load_lds((const __attribute__((address_space(1))) void*)g,
                                     (__attribute__((address_space(3))) void*)l, 16, 0, 0);
}

// ---------------------------------------------------------------------------
// prep: f32 -> bf16 conversions + weight concat + bias concat
// ---------------------------------------------------------------------------
__global__ __launch_bounds__(256)
void prep_convert(const float* __restrict__ x, const float* __restrict__ Wq,
                  const float* __restrict__ Wk, const float* __restrict__ Wv,
                  const float* __restrict__ Wd, const float* __restrict__ pq,
                  const float* __restrict__ bq, const float* __restrict__ bk,
                  const float* __restrict__ bv,
                  bf16* __restrict__ xb, bf16* __restrict__ Wb,
                  bf16* __restrict__ Wdb, bf16* __restrict__ pqb,
                  float* __restrict__ bcat)
{
    size_t i4 = (size_t)blockIdx.x * 256 + threadIdx.x;
    size_t e0 = i4 * 4;
    if (e0 >= 9471488) return;
    const float* src;
    if (e0 < 8388608) {
        src = x + e0;
        float4 v = *(const float4*)src;
        bf16* d = xb + e0;
        d[0] = (bf16)v.x; d[1] = (bf16)v.y; d[2] = (bf16)v.z; d[3] = (bf16)v.w;
    } else if (e0 < 9175040) {
        size_t c = e0 - 8388608; int wsel = (int)(c >> 18); size_t o = c & 262143;
        src = (wsel == 0 ? Wq : wsel == 1 ? Wk : Wv) + o;
        float4 v = *(const float4*)src;
        bf16* d = Wb + c;
        d[0] = (bf16)v.x; d[1] = (bf16)v.y; d[2] = (bf16)v.z; d[3] = (bf16)v.w;
    } else if (e0 < 9437184) {
        size_t c = e0 - 9175040;
        src = Wd + c;
        float4 v = *(const float4*)src;
        bf16* d = Wdb + c;
        d[0] = (bf16)v.x; d[1] = (bf16)v.y; d[2] = (bf16)v.z; d[3] = (bf16)v.w;
    } else if (e0 < 9469952) {
        size_t c = e0 - 9437184;
        src = pq + c;
        float4 v = *(const float4*)src;
        bf16* d = pqb + c;
        d[0] = (bf16)v.x; d[1] = (bf16)v.y; d[2] = (bf16)v.z; d[3] = (bf16)v.w;
    } else {
        size_t c = e0 - 9469952; int wsel = (int)(c >> 9); size_t o = c & 511;
        src = (wsel == 0 ? bq : wsel == 1 ? bk : bv) + o;
        *(float4*)(bcat + c) = *(const float4*)src;
    }
}

// ---------------------------------------------------------------------------
// bf16 MFMA GEMM, C = A * B^T (+bias)(+resid), 128x128 tile, BK=64.
// MODE 0: A=xb16, B=Wcat[1536x512]; Q->bf16 plain; K->bf16 swizzled rows;
//         V->bf16 transposed [bh][e][n] swizzled.
// MODE 1: A=ctxb16, B=Wd; outF f32 = +bias +resid
// ---------------------------------------------------------------------------
template<int MODE>
__global__ __launch_bounds__(256)
void gemm_mfma(const bf16* __restrict__ A, const bf16* __restrict__ Bw,
               const float* __restrict__ bias, const float* __restrict__ resid,
               bf16* __restrict__ outQ, bf16* __restrict__ outK,
               bf16* __restrict__ outV, float* __restrict__ outF)
{
    __shared__ char As[16384];
    __shared__ char Bs[16384];
    const int tid = threadIdx.x;
    const int w = tid >> 6, l = tid & 63;
    const int wr = w >> 1, wc = w & 1;
    const int row0 = blockIdx.y << 7;
    const int col0 = blockIdx.x << 7;

    f32x4 acc[4][4] = {};
    const char* Ab = (const char*)A + (size_t)row0 * 1024;
    const char* Bb = (const char*)Bw + (size_t)col0 * 1024;

    for (int kt = 0; kt < 8; ++kt) {
        const int k0b = kt << 7;
#pragma unroll
        for (int i = 0; i < 4; ++i) {
            int off = (i << 12) + (tid << 4);
            int g = off ^ ((off >> 3) & 0x70);
            int grow = g >> 7, gcol = g & 127;
            gload16(Ab + (size_t)grow * 1024 + k0b + gcol, As + (i << 12) + (w << 10));
            gload16(Bb + (size_t)grow * 1024 + k0b + gcol, Bs + (i << 12) + (w << 10));
        }
        __syncthreads();
#pragma unroll
        for (int ks = 0; ks < 2; ++ks) {
            bf16x8 af[4], bb[4];
#pragma unroll
            for (int mi = 0; mi < 4; ++mi) {
                int row = (wr << 6) + (mi << 4) + (l & 15);
                int addr = ((row << 7) + (ks << 6) + ((l >> 4) << 4)) ^ ((row & 7) << 4);
                af[mi] = *(const bf16x8*)(As + addr);
            }
#pragma unroll
            for (int nj = 0; nj < 4; ++nj) {
                int row = (wc << 6) + (nj << 4) + (l & 15);
                int addr = ((row << 7) + (ks << 6) + ((l >> 4) << 4)) ^ ((row & 7) << 4);
                bb[nj] = *(const bf16x8*)(Bs + addr);
            }
#pragma unroll
            for (int mi = 0; mi < 4; ++mi)
#pragma unroll
                for (int nj = 0; nj < 4; ++nj)
                    acc[mi][nj] = __builtin_amdgcn_mfma_f32_16x16x32_bf16(af[mi], bb[nj], acc[mi][nj], 0, 0, 0);
        }
        __syncthreads();
    }

    const int subrow = (l >> 4) << 2;
    const int subcol = l & 15;
#pragma unroll
    for (int mi = 0; mi < 4; ++mi) {
#pragma unroll
        for (int nj = 0; nj < 4; ++nj) {
            const int cg = col0 + (wc << 6) + (nj << 4) + subcol;
            const float bi = bias[cg];
            const int rgb = row0 + (wr << 6) + (mi << 4) + subrow;
            if (MODE == 0) {
                if (cg < 512) {
#pragma unroll
                    for (int r = 0; r < 4; ++r)
                        outQ[(size_t)(rgb + r) * 512 + cg] = (bf16)(acc[mi][nj][r] + bi);
                } else if (cg < 1024) {
                    const int eg = cg - 512, hh = eg >> 6, ee = eg & 63;
#pragma unroll
                    for (int r = 0; r < 4; ++r) {
                        const int rg = rgb + r;
                        *(bf16*)((char*)outK + (size_t)rg * 1024 + hh * 128 +
                                 ((ee * 2) ^ ((rg & 7) << 4))) = (bf16)(acc[mi][nj][r] + bi);
                    }
                } else {
                    const int eg = cg - 1024, hh = eg >> 6, ee = eg & 63;
                    const int bb2 = rgb >> 12, n = rgb & 4095;
                    bf16x4 pv;
#pragma unroll
                    for (int r = 0; r < 4; ++r) pv[r] = (bf16)(acc[mi][nj][r] + bi);
                    const int nb = n * 2;
                    size_t byteaddr = (size_t)((bb2 * 8 + hh) * 64 + ee) * 8192
                                    + (size_t)((nb & ~127) | ((nb & 127) ^ ((ee & 7) << 4)));
                    *(bf16x4*)((char*)outV + byteaddr) = pv;
                }
            } else {
#pragma unroll
                for (int r = 0; r < 4; ++r) {
                    const int rg = rgb + r;
                    outF[(size_t)rg * 512 + cg] = acc[mi][nj][r] + bi + resid[(size_t)rg * 512 + cg];
                }
            }
        }
    }
}

// ---------------------------------------------------------------------------
// vsum[bh*64+e] = sum_n Vt[bh][e][n] (swizzle is within-row => order-invariant)
// Grid 2048, block 64.
// ---------------------------------------------------------------------------
__global__ __launch_bounds__(64)
void vsum_kernel(const bf16* __restrict__ Vt, float* __restrict__ vsum)
{
    const int row = blockIdx.x;
    const bf16x8* p = (const bf16x8*)((const char*)Vt + (size_t)row * 8192);
    float s = 0.f;
#pragma unroll
    for (int i = 0; i < 8; ++i) {
        bf16x8 v = p[threadIdx.x + i * 64];
#pragma unroll
        for (int u = 0; u < 8; ++u) s += (float)v[u];
    }
    s = warpReduceSum(s);
    if (threadIdx.x == 0) vsum[row] = s;
}

// ---------------------------------------------------------------------------
// kside MFMA: per (bh, 64-m tile): loop n chunks of 128:
//   E[n,m] = exp(NORM * K.projk^T - diag); ctx[m,e] += E^T.V ; esum[m] += E
// Outputs: ctxbT [bh][e][512m] bf16, esum, ctxsum (atomic), esumsum (atomic),
//          gmax (atomicMax). Grid (32, 8), block 256 (4 waves).
// ---------------------------------------------------------------------------
__global__ __launch_bounds__(256)
void kside_mfma(const bf16* __restrict__ Kb, const bf16* __restrict__ Vt,
                const float* __restrict__ projk,
                bf16* __restrict__ ctxbT, float* __restrict__ esum,
                float* __restrict__ ctxsum, float* __restrict__ esumsum,
                float* __restrict__ gmax)
{
    __shared__ char K_s[16384];      // [128 n][128 B] swizzled
    __shared__ char V_s[16384];      // [64 e][256 B] swizzled
    __shared__ char E_s[16384];      // [64 m][256 B] swizzled
    __shared__ float diag_s[128];
    __shared__ float part_s[4][64];
    __shared__ float wmax_s[4];

    const int tid = threadIdx.x;
    const int w = tid >> 6, l = tid & 63;
    const int bh = blockIdx.x;
    const int b = bh >> 3, h = bh & 7;
    const int m0 = blockIdx.y << 6;

    // projk fragments in registers: B[col=m][k=e]
    bf16x8 pk[4][2];
#pragma unroll
    for (int nj = 0; nj < 4; ++nj)
#pragma unroll
        for (int ks = 0; ks < 2; ++ks) {
            const int m = m0 + (nj << 4) + (l & 15);
            const int e0 = (ks << 5) + ((l >> 4) << 3);
            const float* p = projk + (size_t)m * 64 + e0;
            float4 a = *(const float4*)p;
            float4 c = *(const float4*)(p + 4);
            bf16x8 f;
            f[0] = (bf16)a.x; f[1] = (bf16)a.y; f[2] = (bf16)a.z; f[3] = (bf16)a.w;
            f[4] = (bf16)c.x; f[5] = (bf16)c.y; f[6] = (bf16)c.z; f[7] = (bf16)c.w;
            pk[nj][ks] = f;
        }

    const char* kg = (const char*)Kb + ((size_t)(b * 4096) * 512 + h * 64) * 2
                   + (size_t)((w << 3) + (l >> 3)) * 1024 + ((l & 7) << 4);
    const char* vg = (const char*)Vt + (size_t)bh * 64 * 8192
                   + (size_t)((w << 2) + (l >> 4)) * 8192 + ((l & 15) << 4);

    float esacc[4] = {0.f, 0.f, 0.f, 0.f};
    float lmax = -1e30f;
    f32x4 acc2[4] = {};

    for (int c = 0; c < 32; ++c) {
        const int n0 = c << 7;
        // stage K chunk [128][64] bf16 and V^T chunk [64][128] bf16
#pragma unroll
        for (int i = 0; i < 4; ++i) {
            gload16(kg + (size_t)(n0 + (i << 5)) * 1024, K_s + (i << 12) + (w << 10));
            gload16(vg + (size_t)(i << 4) * 8192 + (n0 << 1), V_s + (i << 12) + (w << 10));
        }
        __syncthreads();

        // E-MFMA + in-register diag
        f32x4 acc1[2][4] = {};
        float ss[2] = {0.f, 0.f};
#pragma unroll
        for (int ks = 0; ks < 2; ++ks) {
            bf16x8 af[2];
#pragma unroll
            for (int mi = 0; mi < 2; ++mi) {
                const int n = (w << 5) + (mi << 4) + (l & 15);
                const int addr = ((n << 7) + (ks << 6) + ((l >> 4) << 4)) ^ ((n & 7) << 4);
                af[mi] = *(const bf16x8*)(K_s + addr);
#pragma unroll
                for (int u = 0; u < 8; ++u) { float f = (float)af[mi][u]; ss[mi] += f * f; }
            }
#pragma unroll
            for (int mi = 0; mi < 2; ++mi)
#pragma unroll
                for (int nj = 0; nj < 4; ++nj)
                    acc1[mi][nj] = __builtin_amdgcn_mfma_f32_16x16x32_bf16(af[mi], pk[nj][ks], acc1[mi][nj], 0, 0, 0);
        }
#pragma unroll
        for (int mi = 0; mi < 2; ++mi) {
            float s = ss[mi];
            s += __shfl_xor(s, 16); s += __shfl_xor(s, 32);
            if (l < 16) diag_s[(w << 5) + (mi << 4) + l] = DIAG_C * s;
        }
        // exp -> E_s (bf16, swizzled [m][n]); esacc; lmax   (intra-wave diag dep)
#pragma unroll
        for (int mi = 0; mi < 2; ++mi) {
            const int nrow0 = (w << 5) + (mi << 4) + ((l >> 4) << 2);
#pragma unroll
            for (int nj = 0; nj < 4; ++nj) {
                const int m = (nj << 4) + (l & 15);
                bf16x4 ev;
#pragma unroll
                for (int r = 0; r < 4; ++r) {
                    float kd = NORMALIZER * acc1[mi][nj][r];
                    lmax = fmaxf(lmax, kd);
                    float e = __expf(kd - diag_s[nrow0 + r]);
                    esacc[nj] += e;
                    ev[r] = (bf16)e;
                }
                const int addr = ((m << 8) + (nrow0 << 1)) ^ ((m & 7) << 4);
                *(bf16x4*)(E_s + addr) = ev;
            }
        }
        __syncthreads();

        // ctx-MFMA: wave owns m rows [w*16, w*16+16), all 64 e, K=128
#pragma unroll
        for (int ks = 0; ks < 4; ++ks) {
            const int mrow = (w << 4) + (l & 15);
            const int aaddr = ((mrow << 8) + (ks << 6) + ((l >> 4) << 4)) ^ ((mrow & 7) << 4);
            bf16x8 aE = *(const bf16x8*)(E_s + aaddr);
#pragma unroll
            for (int ej = 0; ej < 4; ++ej) {
                const int e = (ej << 4) + (l & 15);
                const int vaddr = ((e << 8) + (ks << 6) + ((l >> 4) << 4)) ^ ((e & 7) << 4);
                bf16x8 bV = *(const bf16x8*)(V_s + vaddr);
                acc2[ej] = __builtin_amdgcn_mfma_f32_16x16x32_bf16(aE, bV, acc2[ej], 0, 0, 0);
            }
        }
        __syncthreads();
    }

    // ---- epilogue ----
    // esum
#pragma unroll
    for (int nj = 0; nj < 4; ++nj) {
        float s = esacc[nj];
        s += __shfl_xor(s, 16); s += __shfl_xor(s, 32);
        if (l < 16) part_s[w][(nj << 4) + l] = s;
    }
    // gmax
#pragma unroll
    for (int off = 32; off > 0; off >>= 1) lmax = fmaxf(lmax, __shfl_xor(lmax, off));
    if (l == 0) wmax_s[w] = lmax;
    __syncthreads();
    if (tid < 64) {
        float es = part_s[0][tid] + part_s[1][tid] + part_s[2][tid] + part_s[3][tid];
        esum[(size_t)bh * 512 + m0 + tid] = es;
        float t = warpReduceSum(es);
        if (tid == 0) {
            atomicAdd(esumsum + bh, t);
            atomicMaxF(gmax, fmaxf(fmaxf(wmax_s[0], wmax_s[1]), fmaxf(wmax_s[2], wmax_s[3])));
        }
    }
    // ctx write (bf16 [bh][e][512]) + ctxsum
#pragma unroll
    for (int ej = 0; ej < 4; ++ej) {
        const int e = (ej << 4) + (l & 15);
        const int mrow0 = m0 + (w << 4) + ((l >> 4) << 2);
        bf16x4 pv;
        float cs = 0.f;
#pragma unroll
        for (int r = 0; r < 4; ++r) { pv[r] = (bf16)acc2[ej][r]; cs += acc2[ej][r]; }
        *(bf16x4*)((char*)ctxbT + ((size_t)(bh * 64 + e) * 512 + mrow0) * 2) = pv;
        cs += __shfl_xor(cs, 16); cs += __shfl_xor(cs, 32);
        if (l < 16) atomicAdd(ctxsum + bh * 64 + e, cs);
    }
}

// ---------------------------------------------------------------------------
// q-side MFMA (unchanged from round 2)
// ---------------------------------------------------------------------------
__global__ __launch_bounds__(256)
void qside_mfma(const bf16* __restrict__ Qb, const bf16* __restrict__ Pq,
                const bf16* __restrict__ CtxT, const float* __restrict__ esum,
                const float* __restrict__ vsum, const float* __restrict__ ctxsum,
                const float* __restrict__ esumsum, const float* __restrict__ gmax,
                bf16* __restrict__ OutC)
{
    __shared__ char q_s[16384];
    __shared__ char pq_s[16384];
    __shared__ char T_s[128 * 272];
    __shared__ float esum_s[512];
    __shared__ float vsum_s[64];
    __shared__ float ctxsum_s[64];
    __shared__ float diag_s[128];
    __shared__ int   tmax_s[128];
    __shared__ float red_s[256];
    __shared__ float red2_s[256];
    __shared__ float alpha_s[128], g1_s[128], g2_s[128];

    const int tid = threadIdx.x;
    const int w = tid >> 6, l = tid & 63;
    const int wr = w >> 1, wc = w & 1;
    const int bh = blockIdx.x;
    const int b = bh >> 3, h = bh & 7;
    const int n0 = blockIdx.y << 7;

    const char* qg = (const char*)Qb + (((size_t)(b * NSEQ + n0)) * DMODEL + h * DHEAD) * 2;
#pragma unroll
    for (int i = 0; i < 4; ++i) {
        int off = (i << 12) + (tid << 4);
        int g = off ^ ((off >> 3) & 0x70);
        gload16(qg + (size_t)(g >> 7) * 1024 + (g & 127), q_s + (i << 12) + (w << 10));
    }
    if (tid < 64) { vsum_s[tid] = vsum[bh * 64 + tid]; ctxsum_s[tid] = ctxsum[bh * 64 + tid]; }
    esum_s[tid] = esum[bh * 512 + tid];
    esum_s[tid + 256] = esum[bh * 512 + 256 + tid];
    if (tid < 128) tmax_s[tid] = 0;
    __syncthreads();

    {
        const int row = tid >> 1, seg = tid & 1;
        float ss = 0.f;
#pragma unroll
        for (int j = 0; j < 4; ++j) {
            int addr = ((row << 7) + (((seg << 2) + j) << 4)) ^ ((row & 7) << 4);
            bf16x8 v = *(const bf16x8*)(q_s + addr);
#pragma unroll
            for (int u = 0; u < 8; ++u) { float f = (float)v[u]; ss += f * f; }
        }
        red_s[tid] = ss;
    }
    __syncthreads();
    if (tid < 128) diag_s[tid] = DIAG_C * (red_s[2 * tid] + red_s[2 * tid + 1]);
    __syncthreads();

    f32x4 acc2[4][2] = {};
    float uT = 0.f, uE = 0.f;
    const char* ctxg = (const char*)CtxT + (size_t)bh * 64 * 512 * 2;

    for (int ft = 0; ft < 4; ++ft) {
        const char* pg = (const char*)Pq + (size_t)ft * 128 * 128;
#pragma unroll
        for (int i = 0; i < 4; ++i) {
            int off = (i << 12) + (tid << 4);
            int g = off ^ ((off >> 3) & 0x70);
            gload16(pg + g, pq_s + (i << 12) + (w << 10));
        }
        __syncthreads();

        f32x4 acc1[4][4] = {};
#pragma unroll
        for (int ks = 0; ks < 2; ++ks) {
            bf16x8 af[4], bb[4];
#pragma unroll
            for (int mi = 0; mi < 4; ++mi) {
                int row = (wr << 6) + (mi << 4) + (l & 15);
                int addr = ((row << 7) + (ks << 6) + ((l >> 4) << 4)) ^ ((row & 7) << 4);
                af[mi] = *(const bf16x8*)(q_s + addr);
            }
#pragma unroll
            for (int nj = 0; nj < 4; ++nj) {
                int fr = (wc << 6) + (nj << 4) + (l & 15);
                int addr = ((fr << 7) + (ks << 6) + ((l >> 4) << 4)) ^ ((fr & 7) << 4);
                bb[nj] = *(const bf16x8*)(pq_s + addr);
            }
#pragma unroll
            for (int mi = 0; mi < 4; ++mi)
#pragma unroll
                for (int nj = 0; nj < 4; ++nj)
                    acc1[mi][nj] = __builtin_amdgcn_mfma_f32_16x16x32_bf16(af[mi], bb[nj], acc1[mi][nj], 0, 0, 0);
        }

#pragma unroll
        for (int mi = 0; mi < 4; ++mi) {
#pragma unroll
            for (int r = 0; r < 4; ++r) {
                const int row = (wr << 6) + (mi << 4) + ((l >> 4) << 2) + r;
                const float dg = diag_s[row];
                float tmx = 0.f;
#pragma unroll
                for (int nj = 0; nj < 4; ++nj) {
                    int m = (wc << 6) + (nj << 4) + (l & 15);
                    float t = __expf(NORMALIZER * acc1[mi][nj][r] - dg);
                    tmx = fmaxf(tmx, t);
                    *(bf16*)(T_s + row * 272 + m * 2) = (bf16)t;
                }
#pragma unroll
                for (int m2 = 1; m2 < 16; m2 <<= 1) tmx = fmaxf(tmx, __shfl_xor(tmx, m2));
                if ((l & 15) == 0) atomicMax(&tmax_s[row], __float_as_int(tmx));
            }
        }
        __syncthreads();

        {
            bf16x8 bfr[4][2];
#pragma unroll
            for (int ks = 0; ks < 4; ++ks)
#pragma unroll
                for (int nj = 0; nj < 2; ++nj) {
                    int e = (wc << 5) + (nj << 4) + (l & 15);
                    size_t go = (((size_t)e * 512) + (ft << 7) + (ks << 5) + ((l >> 4) << 3)) * 2;
                    bfr[ks][nj] = *(const bf16x8*)(ctxg + go);
                }
#pragma unroll
            for (int ks = 0; ks < 4; ++ks) {
                bf16x8 af[4];
#pragma unroll
                for (int mi = 0; mi < 4; ++mi) {
                    int row = (wr << 6) + (mi << 4) + (l & 15);
                    af[mi] = *(const bf16x8*)(T_s + row * 272 + (ks << 6) + ((l >> 4) << 4));
                }
#pragma unroll
                for (int mi = 0; mi < 4; ++mi)
#pragma unroll
                    for (int nj = 0; nj < 2; ++nj)
                        acc2[mi][nj] = __builtin_amdgcn_mfma_f32_16x16x32_bf16(af[mi], bfr[ks][nj], acc2[mi][nj], 0, 0, 0);
            }
        }

        {
            const int row = tid >> 1, seg = tid & 1;
            const float* es = esum_s + (ft << 7) + (seg << 6);
            const char* tb = T_s + row * 272 + (seg << 7);
#pragma unroll
            for (int c8 = 0; c8 < 8; ++c8) {
                bf16x8 v = *(const bf16x8*)(tb + (c8 << 4));
#pragma unroll
                for (int u = 0; u < 8; ++u) {
                    float f = (float)v[u];
                    uT += f;
                    uE += f * es[(c8 << 3) + u];
                }
            }
        }
    }
    __syncthreads();

    red_s[tid] = uT; red2_s[tid] = uE;
    __syncthreads();
    if (tid < 128) {
        const float sG = __expf(-gmax[0]);
        const float ess = esumsum[bh];
        float uTr = red_s[2 * tid] + red_s[2 * tid + 1];
        float uEr = red2_s[2 * tid] + red2_s[2 * tid + 1];
        float tmax = __int_as_float(tmax_s[tid]);
        float cr = __expf(-diag_s[tid]) / tmax;
        float qsum = cr * uTr + KEPS * 512.0f;
        float denom = sG * (cr * uEr + KEPS * ess) + KEPS * 4096.0f * qsum;
        float inv = 1.0f / denom;
        alpha_s[tid] = sG * cr * inv;
        g1_s[tid] = sG * KEPS * inv;
        g2_s[tid] = KEPS * qsum * inv;
    }
    __syncthreads();

    bf16* outbase = OutC + ((size_t)(b * NSEQ + n0)) * DMODEL + h * DHEAD;
#pragma unroll
    for (int mi = 0; mi < 4; ++mi)
#pragma unroll
        for (int r = 0; r < 4; ++r) {
            const int row = (wr << 6) + (mi << 4) + ((l >> 4) << 2) + r;
            const float al = alpha_s[row], G1 = g1_s[row], G2 = g2_s[row];
#pragma unroll
            for (int nj = 0; nj < 2; ++nj) {
                int e = (wc << 5) + (nj << 4) + (l & 15);
                float v = al * acc2[mi][nj][r] + G1 * ctxsum_s[e] + G2 * vsum_s[e];
                outbase[(size_t)row * DMODEL + e] = (bf16)v;
            }
        }
}

// ---------------------------------------------------------------------------
// LayerNorm over D=512, 1 wave per row.
// ---------------------------------------------------------------------------
__global__ __launch_bounds__(64)
void ln_kernel(const float* __restrict__ hid, const float* __restrict__ gamma,
               const float* __restrict__ beta, float* __restrict__ out)
{
    const int row = blockIdx.x;
    const int lane = threadIdx.x;
    const float* x = hid + (size_t)row * DMODEL + (lane << 3);
    float4 a = *(const float4*)x;
    float4 c = *(const float4*)(x + 4);
    float s = a.x + a.y + a.z + a.w + c.x + c.y + c.z + c.w;
    float sq = a.x * a.x + a.y * a.y + a.z * a.z + a.w * a.w +
               c.x * c.x + c.y * c.y + c.z * c.z + c.w * c.w;
    s = warpReduceSum(s);
    sq = warpReduceSum(sq);
    const float mu = s * 0.001953125f;
    const float var = sq * 0.001953125f - mu * mu;
    const float rs = rsqrtf(var + 1e-12f);
    const float4 g1 = *(const float4*)(gamma + (lane << 3));
    const float4 g2 = *(const float4*)(gamma + (lane << 3) + 4);
    const float4 b1 = *(const float4*)(beta + (lane << 3));
    const float4 b2 = *(const float4*)(beta + (lane << 3) + 4);
    float4 o1, o2;
    o1.x = (a.x - mu) * rs * g1.x + b1.x;
    o1.y = (a.y - mu) * rs * g1.y + b1.y;
    o1.z = (a.z - mu) * rs * g1.z + b1.z;
    o1.w = (a.w - mu) * rs * g1.w + b1.w;
    o2.x = (c.x - mu) * rs * g2.x + b2.x;
    o2.y = (c.y - mu) * rs * g2.y + b2.y;
    o2.z = (c.z - mu) * rs * g2.z + b2.z;
    o2.w = (c.w - mu) * rs * g2.w + b2.w;
    *(float4*)(out + (size_t)row * DMODEL + (lane << 3)) = o1;
    *(float4*)(out + (size_t)row * DMODEL + (lane << 3) + 4) = o2;
}

__global__ void init_misc(float* gmax)
{
    if (threadIdx.x == 0 && blockIdx.x == 0) *gmax = -1e30f;
}

// ---------------------------------------------------------------------------
extern "C" void kernel_launch(void* const* d_in, const int* in_sizes, int n_in,
                              void* d_out, int out_size, void* d_ws, size_t ws_size,
                              hipStream_t stream)
{
    const float* x     = (const float*)d_in[0];
    const float* Wq    = (const float*)d_in[2];
    const float* bq    = (const float*)d_in[3];
    const float* Wk    = (const float*)d_in[4];
    const float* bk    = (const float*)d_in[5];
    const float* Wv    = (const float*)d_in[6];
    const float* bv    = (const float*)d_in[7];
    const float* projq = (const float*)d_in[8];
    const float* projk = (const float*)d_in[9];
    const float* Wd    = (const float*)d_in[10];
    const float* bd    = (const float*)d_in[11];
    const float* gamma = (const float*)d_in[12];
    const float* beta  = (const float*)d_in[13];

    char* W = (char*)d_ws;
    bf16*  qb16   = (bf16*) (W);                   // 16 MB
    bf16*  kb16s  = (bf16*) (W + 16777216);        // 16 MB (swizzled rows)
    bf16*  vtb    = (bf16*) (W + 33554432);        // 16 MB (transposed+swizzled)
    bf16*  xb16   = (bf16*) (W + 50331648);        // 16 MB (x bf16, later ctx bf16)
    float* hidf32 = (float*)(W + 67108864);        // 32 MB
    bf16*  Wb16   = (bf16*) (W + 100663296);       // 1.5 MB
    bf16*  Wdb16  = (bf16*) (W + 102236160);       // 0.5 MB
    bf16*  pqb16  = (bf16*) (W + 102760448);       // 64 KB
    float* bcat   = (float*)(W + 102825984);       // 6 KB
    bf16*  ctxbT  = (bf16*) (W + 102832128);       // 2 MB
    float* esumb  = (float*)(W + 104929280);       // 64 KB
    float* vsumb  = (float*)(W + 104994816);       // 8 KB
    float* ctxsum = (float*)(W + 105003008);       // 8 KB
    float* esmsm  = (float*)(W + 105011200);       // 128 B
    float* gmaxb  = (float*)(W + 105011328);       // 4 B

    prep_convert<<<9250, 256, 0, stream>>>(x, Wq, Wk, Wv, Wd, projq, bq, bk, bv,
                                           xb16, Wb16, Wdb16, pqb16, bcat);
    hipMemsetAsync(ctxsum, 0, 8192 + 128, stream);
    init_misc<<<1, 64, 0, stream>>>(gmaxb);

    gemm_mfma<0><<<dim3(12, 128), 256, 0, stream>>>(xb16, Wb16, bcat, nullptr,
                                                    qb16, kb16s, vtb, nullptr);

    vsum_kernel<<<2048, 64, 0, stream>>>(vtb, vsumb);
    kside_mfma<<<dim3(32, 8), 256, 0, stream>>>(kb16s, vtb, projk, ctxbT, esumb,
                                                ctxsum, esmsm, gmaxb);
    qside_mfma<<<dim3(32, 32), 256, 0, stream>>>(qb16, pqb16, ctxbT, esumb, vsumb,
                                                 ctxsum, esmsm, gmaxb, xb16);

    gemm_mfma<1><<<dim3(4, 128), 256, 0, stream>>>(xb16, Wdb16, bd, x,
                                                   nullptr, nullptr, nullptr, hidf32);
    ln_kernel<<<16384, 64, 0, stream>>>(hidf32, gamma, beta, (float*)d_out);
}

// Round 4
// 243.977 us; speedup vs baseline: 7.6044x; 1.1079x over previous
//
#include <hip/hip_runtime.h>
#include <math.h>

typedef __bf16 bf16;
typedef __bf16 bf16x8 __attribute__((ext_vector_type(8)));
typedef __bf16 bf16x4 __attribute__((ext_vector_type(4)));
typedef float  f32x4  __attribute__((ext_vector_type(4)));

#define NSEQ 4096
#define DMODEL 512
#define DHEAD 64
#define MFEAT 512
#define BHEADS 32
#define ROWS_TOTAL 16384

#define NORMALIZER 0.35355339059327373f
#define DIAG_C 0.0625f
#define KEPS 1e-4f

__device__ __forceinline__ float warpReduceSum(float v) {
#pragma unroll
    for (int off = 32; off > 0; off >>= 1) v += __shfl_xor(v, off);
    return v;
}

__device__ __forceinline__ void atomicMaxF(float* addr, float val) {
    int* ai = (int*)addr;
    int cur = __float_as_int(*addr);
    while (__int_as_float(cur) < val) {
        int prev = atomicCAS(ai, cur, __float_as_int(val));
        if (prev == cur) break;
        cur = prev;
    }
}

__device__ __forceinline__ void gload16(const void* g, void* l) {
    __builtin_amdgcn_global_load_lds((const __attribute__((address_space(1))) void*)g,
                                     (__attribute__((address_space(3))) void*)l, 16, 0, 0);
}

// ---------------------------------------------------------------------------
// prep: f32 -> bf16 conversions + weight concat + bias concat
// ---------------------------------------------------------------------------
__global__ __launch_bounds__(256)
void prep_convert(const float* __restrict__ x, const float* __restrict__ Wq,
                  const float* __restrict__ Wk, const float* __restrict__ Wv,
                  const float* __restrict__ Wd, const float* __restrict__ pq,
                  const float* __restrict__ bq, const float* __restrict__ bk,
                  const float* __restrict__ bv,
                  bf16* __restrict__ xb, bf16* __restrict__ Wb,
                  bf16* __restrict__ Wdb, bf16* __restrict__ pqb,
                  float* __restrict__ bcat)
{
    size_t i4 = (size_t)blockIdx.x * 256 + threadIdx.x;
    size_t e0 = i4 * 4;
    if (e0 >= 9471488) return;
    const float* src;
    if (e0 < 8388608) {
        src = x + e0;
        float4 v = *(const float4*)src;
        bf16* d = xb + e0;
        d[0] = (bf16)v.x; d[1] = (bf16)v.y; d[2] = (bf16)v.z; d[3] = (bf16)v.w;
    } else if (e0 < 9175040) {
        size_t c = e0 - 8388608; int wsel = (int)(c >> 18); size_t o = c & 262143;
        src = (wsel == 0 ? Wq : wsel == 1 ? Wk : Wv) + o;
        float4 v = *(const float4*)src;
        bf16* d = Wb + c;
        d[0] = (bf16)v.x; d[1] = (bf16)v.y; d[2] = (bf16)v.z; d[3] = (bf16)v.w;
    } else if (e0 < 9437184) {
        size_t c = e0 - 9175040;
        src = Wd + c;
        float4 v = *(const float4*)src;
        bf16* d = Wdb + c;
        d[0] = (bf16)v.x; d[1] = (bf16)v.y; d[2] = (bf16)v.z; d[3] = (bf16)v.w;
    } else if (e0 < 9469952) {
        size_t c = e0 - 9437184;
        src = pq + c;
        float4 v = *(const float4*)src;
        bf16* d = pqb + c;
        d[0] = (bf16)v.x; d[1] = (bf16)v.y; d[2] = (bf16)v.z; d[3] = (bf16)v.w;
    } else {
        size_t c = e0 - 9469952; int wsel = (int)(c >> 9); size_t o = c & 511;
        src = (wsel == 0 ? bq : wsel == 1 ? bk : bv) + o;
        *(float4*)(bcat + c) = *(const float4*)src;
    }
}

// ---------------------------------------------------------------------------
// bf16 MFMA GEMM, C = A * B^T (+bias)(+resid), 128x128 tile, BK=64.
// MODE 0: A=xb16, B=Wcat[1536x512]; Q->bf16 plain; K->bf16 swizzled rows;
//         V->bf16 transposed [bh][e][n] swizzled.
// MODE 1: A=ctxb16, B=Wd; outF f32 = +bias +resid
// ---------------------------------------------------------------------------
template<int MODE>
__global__ __launch_bounds__(256)
void gemm_mfma(const bf16* __restrict__ A, const bf16* __restrict__ Bw,
               const float* __restrict__ bias, const float* __restrict__ resid,
               bf16* __restrict__ outQ, bf16* __restrict__ outK,
               bf16* __restrict__ outV, float* __restrict__ outF)
{
    __shared__ char As[16384];
    __shared__ char Bs[16384];
    const int tid = threadIdx.x;
    const int w = tid >> 6, l = tid & 63;
    const int wr = w >> 1, wc = w & 1;
    const int row0 = blockIdx.y << 7;
    const int col0 = blockIdx.x << 7;

    f32x4 acc[4][4] = {};
    const char* Ab = (const char*)A + (size_t)row0 * 1024;
    const char* Bb = (const char*)Bw + (size_t)col0 * 1024;

    for (int kt = 0; kt < 8; ++kt) {
        const int k0b = kt << 7;
#pragma unroll
        for (int i = 0; i < 4; ++i) {
            int off = (i << 12) + (tid << 4);
            int g = off ^ ((off >> 3) & 0x70);
            int grow = g >> 7, gcol = g & 127;
            gload16(Ab + (size_t)grow * 1024 + k0b + gcol, As + (i << 12) + (w << 10));
            gload16(Bb + (size_t)grow * 1024 + k0b + gcol, Bs + (i << 12) + (w << 10));
        }
        __syncthreads();
#pragma unroll
        for (int ks = 0; ks < 2; ++ks) {
            bf16x8 af[4], bb[4];
#pragma unroll
            for (int mi = 0; mi < 4; ++mi) {
                int row = (wr << 6) + (mi << 4) + (l & 15);
                int addr = ((row << 7) + (ks << 6) + ((l >> 4) << 4)) ^ ((row & 7) << 4);
                af[mi] = *(const bf16x8*)(As + addr);
            }
#pragma unroll
            for (int nj = 0; nj < 4; ++nj) {
                int row = (wc << 6) + (nj << 4) + (l & 15);
                int addr = ((row << 7) + (ks << 6) + ((l >> 4) << 4)) ^ ((row & 7) << 4);
                bb[nj] = *(const bf16x8*)(Bs + addr);
            }
#pragma unroll
            for (int mi = 0; mi < 4; ++mi)
#pragma unroll
                for (int nj = 0; nj < 4; ++nj)
                    acc[mi][nj] = __builtin_amdgcn_mfma_f32_16x16x32_bf16(af[mi], bb[nj], acc[mi][nj], 0, 0, 0);
        }
        __syncthreads();
    }

    const int subrow = (l >> 4) << 2;
    const int subcol = l & 15;
#pragma unroll
    for (int mi = 0; mi < 4; ++mi) {
#pragma unroll
        for (int nj = 0; nj < 4; ++nj) {
            const int cg = col0 + (wc << 6) + (nj << 4) + subcol;
            const float bi = bias[cg];
            const int rgb = row0 + (wr << 6) + (mi << 4) + subrow;
            if (MODE == 0) {
                if (cg < 512) {
#pragma unroll
                    for (int r = 0; r < 4; ++r)
                        outQ[(size_t)(rgb + r) * 512 + cg] = (bf16)(acc[mi][nj][r] + bi);
                } else if (cg < 1024) {
                    const int eg = cg - 512, hh = eg >> 6, ee = eg & 63;
#pragma unroll
                    for (int r = 0; r < 4; ++r) {
                        const int rg = rgb + r;
                        *(bf16*)((char*)outK + (size_t)rg * 1024 + hh * 128 +
                                 ((ee * 2) ^ ((rg & 7) << 4))) = (bf16)(acc[mi][nj][r] + bi);
                    }
                } else {
                    const int eg = cg - 1024, hh = eg >> 6, ee = eg & 63;
                    const int bb2 = rgb >> 12, n = rgb & 4095;
                    bf16x4 pv;
#pragma unroll
                    for (int r = 0; r < 4; ++r) pv[r] = (bf16)(acc[mi][nj][r] + bi);
                    const int nb = n * 2;
                    size_t byteaddr = (size_t)((bb2 * 8 + hh) * 64 + ee) * 8192
                                    + (size_t)((nb & ~127) | ((nb & 127) ^ ((ee & 7) << 4)));
                    *(bf16x4*)((char*)outV + byteaddr) = pv;
                }
            } else {
#pragma unroll
                for (int r = 0; r < 4; ++r) {
                    const int rg = rgb + r;
                    outF[(size_t)rg * 512 + cg] = acc[mi][nj][r] + bi + resid[(size_t)rg * 512 + cg];
                }
            }
        }
    }
}

// ---------------------------------------------------------------------------
// vsum[bh*64+e] = sum_n Vt[bh][e][n]. Grid 2048, block 64.
// ---------------------------------------------------------------------------
__global__ __launch_bounds__(64)
void vsum_kernel(const bf16* __restrict__ Vt, float* __restrict__ vsum)
{
    const int row = blockIdx.x;
    const bf16x8* p = (const bf16x8*)((const char*)Vt + (size_t)row * 8192);
    float s = 0.f;
#pragma unroll
    for (int i = 0; i < 8; ++i) {
        bf16x8 v = p[threadIdx.x + i * 64];
#pragma unroll
        for (int u = 0; u < 8; ++u) s += (float)v[u];
    }
    s = warpReduceSum(s);
    if (threadIdx.x == 0) vsum[row] = s;
}

// ---------------------------------------------------------------------------
// kside MFMA: per (bh, 64-m tile): loop n chunks of 128:
//   E[n,m] = exp(NORM * K.projk^T - diag); ctx[m,e] += E^T.V ; esum[m] += E
// Outputs into ctxE [bh][80][512] bf16: rows 0-63 = ctx^T, row 64 = ones,
// row 65 = esum. Plus ctxsum (atomic), esumsum (atomic), gmax (atomicMax).
// Grid (32, 8), block 256 (4 waves).
// ---------------------------------------------------------------------------
__global__ __launch_bounds__(256)
void kside_mfma(const bf16* __restrict__ Kb, const bf16* __restrict__ Vt,
                const float* __restrict__ projk,
                bf16* __restrict__ ctxE, float* __restrict__ ctxsum,
                float* __restrict__ esumsum, float* __restrict__ gmax)
{
    __shared__ char K_s[16384];      // [128 n][128 B] swizzled
    __shared__ char V_s[16384];      // [64 e][256 B] swizzled
    __shared__ char E_s[16384];      // [64 m][256 B] swizzled
    __shared__ float diag_s[128];
    __shared__ float part_s[4][64];
    __shared__ float wmax_s[4];

    const int tid = threadIdx.x;
    const int w = tid >> 6, l = tid & 63;
    const int bh = blockIdx.x;
    const int b = bh >> 3, h = bh & 7;
    const int m0 = blockIdx.y << 6;

    bf16x8 pk[4][2];
#pragma unroll
    for (int nj = 0; nj < 4; ++nj)
#pragma unroll
        for (int ks = 0; ks < 2; ++ks) {
            const int m = m0 + (nj << 4) + (l & 15);
            const int e0 = (ks << 5) + ((l >> 4) << 3);
            const float* p = projk + (size_t)m * 64 + e0;
            float4 a = *(const float4*)p;
            float4 c = *(const float4*)(p + 4);
            bf16x8 f;
            f[0] = (bf16)a.x; f[1] = (bf16)a.y; f[2] = (bf16)a.z; f[3] = (bf16)a.w;
            f[4] = (bf16)c.x; f[5] = (bf16)c.y; f[6] = (bf16)c.z; f[7] = (bf16)c.w;
            pk[nj][ks] = f;
        }

    const char* kg = (const char*)Kb + ((size_t)(b * 4096) * 512 + h * 64) * 2
                   + (size_t)((w << 3) + (l >> 3)) * 1024 + ((l & 7) << 4);
    const char* vg = (const char*)Vt + (size_t)bh * 64 * 8192
                   + (size_t)((w << 2) + (l >> 4)) * 8192 + ((l & 15) << 4);

    float esacc[4] = {0.f, 0.f, 0.f, 0.f};
    float lmax = -1e30f;
    f32x4 acc2[4] = {};

    for (int c = 0; c < 32; ++c) {
        const int n0 = c << 7;
#pragma unroll
        for (int i = 0; i < 4; ++i) {
            gload16(kg + (size_t)(n0 + (i << 5)) * 1024, K_s + (i << 12) + (w << 10));
            gload16(vg + (size_t)(i << 4) * 8192 + (n0 << 1), V_s + (i << 12) + (w << 10));
        }
        __syncthreads();

        f32x4 acc1[2][4] = {};
        float ss[2] = {0.f, 0.f};
#pragma unroll
        for (int ks = 0; ks < 2; ++ks) {
            bf16x8 af[2];
#pragma unroll
            for (int mi = 0; mi < 2; ++mi) {
                const int n = (w << 5) + (mi << 4) + (l & 15);
                const int addr = ((n << 7) + (ks << 6) + ((l >> 4) << 4)) ^ ((n & 7) << 4);
                af[mi] = *(const bf16x8*)(K_s + addr);
#pragma unroll
                for (int u = 0; u < 8; ++u) { float f = (float)af[mi][u]; ss[mi] += f * f; }
            }
#pragma unroll
            for (int mi = 0; mi < 2; ++mi)
#pragma unroll
                for (int nj = 0; nj < 4; ++nj)
                    acc1[mi][nj] = __builtin_amdgcn_mfma_f32_16x16x32_bf16(af[mi], pk[nj][ks], acc1[mi][nj], 0, 0, 0);
        }
#pragma unroll
        for (int mi = 0; mi < 2; ++mi) {
            float s = ss[mi];
            s += __shfl_xor(s, 16); s += __shfl_xor(s, 32);
            if (l < 16) diag_s[(w << 5) + (mi << 4) + l] = DIAG_C * s;
        }
#pragma unroll
        for (int mi = 0; mi < 2; ++mi) {
            const int nrow0 = (w << 5) + (mi << 4) + ((l >> 4) << 2);
#pragma unroll
            for (int nj = 0; nj < 4; ++nj) {
                const int m = (nj << 4) + (l & 15);
                bf16x4 ev;
#pragma unroll
                for (int r = 0; r < 4; ++r) {
                    float kd = NORMALIZER * acc1[mi][nj][r];
                    lmax = fmaxf(lmax, kd);
                    float e = __expf(kd - diag_s[nrow0 + r]);
                    esacc[nj] += e;
                    ev[r] = (bf16)e;
                }
                const int addr = ((m << 8) + (nrow0 << 1)) ^ ((m & 7) << 4);
                *(bf16x4*)(E_s + addr) = ev;
            }
        }
        __syncthreads();

#pragma unroll
        for (int ks = 0; ks < 4; ++ks) {
            const int mrow = (w << 4) + (l & 15);
            const int aaddr = ((mrow << 8) + (ks << 6) + ((l >> 4) << 4)) ^ ((mrow & 7) << 4);
            bf16x8 aE = *(const bf16x8*)(E_s + aaddr);
#pragma unroll
            for (int ej = 0; ej < 4; ++ej) {
                const int e = (ej << 4) + (l & 15);
                const int vaddr = ((e << 8) + (ks << 6) + ((l >> 4) << 4)) ^ ((e & 7) << 4);
                bf16x8 bV = *(const bf16x8*)(V_s + vaddr);
                acc2[ej] = __builtin_amdgcn_mfma_f32_16x16x32_bf16(aE, bV, acc2[ej], 0, 0, 0);
            }
        }
        __syncthreads();
    }

    // ---- epilogue ----
#pragma unroll
    for (int nj = 0; nj < 4; ++nj) {
        float s = esacc[nj];
        s += __shfl_xor(s, 16); s += __shfl_xor(s, 32);
        if (l < 16) part_s[w][(nj << 4) + l] = s;
    }
#pragma unroll
    for (int off = 32; off > 0; off >>= 1) lmax = fmaxf(lmax, __shfl_xor(lmax, off));
    if (l == 0) wmax_s[w] = lmax;
    __syncthreads();
    if (tid < 64) {
        float es = part_s[0][tid] + part_s[1][tid] + part_s[2][tid] + part_s[3][tid];
        bf16* er = ctxE + (size_t)(bh * 80 + 64) * 512 + m0;
        er[tid] = (bf16)1.0f;          // ones row (64)
        er[512 + tid] = (bf16)es;      // esum row (65)
        float t = warpReduceSum(es);
        if (tid == 0) {
            atomicAdd(esumsum + bh, t);
            atomicMaxF(gmax, fmaxf(fmaxf(wmax_s[0], wmax_s[1]), fmaxf(wmax_s[2], wmax_s[3])));
        }
    }
#pragma unroll
    for (int ej = 0; ej < 4; ++ej) {
        const int e = (ej << 4) + (l & 15);
        const int mrow0 = m0 + (w << 4) + ((l >> 4) << 2);
        bf16x4 pv;
        float cs = 0.f;
#pragma unroll
        for (int r = 0; r < 4; ++r) { pv[r] = (bf16)acc2[ej][r]; cs += acc2[ej][r]; }
        *(bf16x4*)((char*)ctxE + ((size_t)(bh * 80 + e) * 512 + mrow0) * 2) = pv;
        cs += __shfl_xor(cs, 16); cs += __shfl_xor(cs, 32);
        if (l < 16) atomicAdd(ctxsum + bh * 64 + e, cs);
    }
}

// ---------------------------------------------------------------------------
// q-side v2: barrier-free, wave-private 32-row slices, direct-global frags.
// Phase 1: qdash = q.projq^T (K=64); T = exp(NORM*qdash - diag) -> T_s.
// Phase 2: acc2 += T * ctxE^T (80 cols: 64 ctx + ones + esum).
// Grid (32 bh, 32 ntiles), block 256 (4 waves).
// ---------------------------------------------------------------------------
__global__ __launch_bounds__(256)
void qside_mfma2(const bf16* __restrict__ Qb, const bf16* __restrict__ Pq,
                 const bf16* __restrict__ CtxE, const float* __restrict__ vsum,
                 const float* __restrict__ ctxsum, const float* __restrict__ esumsum,
                 const float* __restrict__ gmax, bf16* __restrict__ OutC)
{
    __shared__ char T_s[128 * 272];   // [128 rows][136 bf16], wave-private slices

    const int tid = threadIdx.x;
    const int w = tid >> 6, l = tid & 63;
    const int lq = l & 15, lg = l >> 4;
    const int bh = blockIdx.x;
    const int b = bh >> 3, h = bh & 7;
    const int n0 = blockIdx.y << 7;

    // A-frags (q rows (w<<5)+(mi<<4)+lq) + in-register diag
    bf16x8 qa[2][2];
    float ss[2] = {0.f, 0.f};
#pragma unroll
    for (int mi = 0; mi < 2; ++mi) {
        const int n = n0 + (w << 5) + (mi << 4) + lq;
        const char* qr = (const char*)Qb + ((size_t)(b * 4096 + n) * 512 + h * 64) * 2;
#pragma unroll
        for (int ks = 0; ks < 2; ++ks) {
            qa[mi][ks] = *(const bf16x8*)(qr + ((ks << 5) + (lg << 3)) * 2);
#pragma unroll
            for (int u = 0; u < 8; ++u) { float f = (float)qa[mi][ks][u]; ss[mi] += f * f; }
        }
        ss[mi] += __shfl_xor(ss[mi], 16);
        ss[mi] += __shfl_xor(ss[mi], 32);   // replicated over lg for row lq
    }
    // diag for this lane's C-rows (row = mi*16 + lg*4 + r): pull from lane lg*4+r
    float dgc[2][4];
#pragma unroll
    for (int mi = 0; mi < 2; ++mi)
#pragma unroll
        for (int r = 0; r < 4; ++r)
            dgc[mi][r] = DIAG_C * __shfl(ss[mi], (lg << 2) + r);

    f32x4 acc2[2][5] = {};
    float mmax[2][4];
#pragma unroll
    for (int mi = 0; mi < 2; ++mi)
#pragma unroll
        for (int r = 0; r < 4; ++r) mmax[mi][r] = -1e30f;

    const char* ctxg = (const char*)CtxE + (size_t)bh * 80 * 512 * 2;

    for (int ft = 0; ft < 4; ++ft) {
        // ---- phase 1: qdash for 128 features ----
        f32x4 acc1[2][8] = {};
#pragma unroll
        for (int ks = 0; ks < 2; ++ks) {
            bf16x8 pf[8];
#pragma unroll
            for (int nj = 0; nj < 8; ++nj) {
                const int feat = (ft << 7) + (nj << 4) + lq;
                pf[nj] = *(const bf16x8*)((const char*)Pq + ((size_t)feat * 64 + (ks << 5) + (lg << 3)) * 2);
            }
#pragma unroll
            for (int nj = 0; nj < 8; ++nj)
#pragma unroll
                for (int mi = 0; mi < 2; ++mi)
                    acc1[mi][nj] = __builtin_amdgcn_mfma_f32_16x16x32_bf16(qa[mi][ks], pf[nj], acc1[mi][nj], 0, 0, 0);
        }
        // ---- exp -> T_s (wave-private rows), rowmax in regs ----
#pragma unroll
        for (int mi = 0; mi < 2; ++mi) {
            const int row0r = (w << 5) + (mi << 4) + (lg << 2);
#pragma unroll
            for (int nj = 0; nj < 8; ++nj) {
                const int m = (nj << 4) + lq;
#pragma unroll
                for (int r = 0; r < 4; ++r) {
                    float qd = acc1[mi][nj][r];
                    mmax[mi][r] = fmaxf(mmax[mi][r], qd);
                    float t = __expf(NORMALIZER * qd - dgc[mi][r]);
                    *(bf16*)(T_s + (row0r + r) * 272 + m * 2) = (bf16)t;
                }
            }
        }
        // ---- phase 2: acc2 += T * ctxE^T (K=128 this ft) ----
#pragma unroll
        for (int ks2 = 0; ks2 < 4; ++ks2) {
            bf16x8 ta[2];
#pragma unroll
            for (int mi = 0; mi < 2; ++mi) {
                const int row = (w << 5) + (mi << 4) + lq;
                ta[mi] = *(const bf16x8*)(T_s + row * 272 + (ks2 << 6) + (lg << 4));
            }
#pragma unroll
            for (int nj2 = 0; nj2 < 5; ++nj2) {
                const int e = (nj2 << 4) + lq;
                bf16x8 cb = *(const bf16x8*)(ctxg + ((size_t)e * 512 + (ft << 7) + (ks2 << 5) + (lg << 3)) * 2);
#pragma unroll
                for (int mi = 0; mi < 2; ++mi)
                    acc2[mi][nj2] = __builtin_amdgcn_mfma_f32_16x16x32_bf16(ta[mi], cb, acc2[mi][nj2], 0, 0, 0);
            }
        }
    }

    // ---- epilogue (all in-register; uT=col64, uE=col65) ----
    const float sG = __expf(-gmax[0]);
    const float ess = esumsum[bh];
    bf16* outb = OutC + ((size_t)(b * 4096 + n0)) * 512 + h * 64;
#pragma unroll
    for (int mi = 0; mi < 2; ++mi) {
#pragma unroll
        for (int r = 0; r < 4; ++r) {
            float mm = mmax[mi][r];
            mm = fmaxf(mm, __shfl_xor(mm, 1));
            mm = fmaxf(mm, __shfl_xor(mm, 2));
            mm = fmaxf(mm, __shfl_xor(mm, 4));
            mm = fmaxf(mm, __shfl_xor(mm, 8));
            const float uT = __shfl(acc2[mi][4][r], l & 48);
            const float uE = __shfl(acc2[mi][4][r], (l & 48) | 1);
            const float cr = __expf(-NORMALIZER * mm);     // e^{-diag}/Tmax
            const float qsum = cr * uT + KEPS * 512.0f;
            const float D = sG * (cr * uE + KEPS * ess) + KEPS * 4096.0f * qsum;
            const float inv = 1.0f / D;
            const float al = sG * cr * inv;
            const float G1 = sG * KEPS * inv;
            const float G2 = KEPS * qsum * inv;
            const int row = (w << 5) + (mi << 4) + (lg << 2) + r;
#pragma unroll
            for (int nj2 = 0; nj2 < 4; ++nj2) {
                const int e = (nj2 << 4) + lq;
                float v = al * acc2[mi][nj2][r] + G1 * ctxsum[bh * 64 + e] + G2 * vsum[bh * 64 + e];
                outb[(size_t)row * 512 + e] = (bf16)v;
            }
        }
    }
}

// ---------------------------------------------------------------------------
// LayerNorm over D=512, 1 wave per row.
// ---------------------------------------------------------------------------
__global__ __launch_bounds__(64)
void ln_kernel(const float* __restrict__ hid, const float* __restrict__ gamma,
               const float* __restrict__ beta, float* __restrict__ out)
{
    const int row = blockIdx.x;
    const int lane = threadIdx.x;
    const float* x = hid + (size_t)row * DMODEL + (lane << 3);
    float4 a = *(const float4*)x;
    float4 c = *(const float4*)(x + 4);
    float s = a.x + a.y + a.z + a.w + c.x + c.y + c.z + c.w;
    float sq = a.x * a.x + a.y * a.y + a.z * a.z + a.w * a.w +
               c.x * c.x + c.y * c.y + c.z * c.z + c.w * c.w;
    s = warpReduceSum(s);
    sq = warpReduceSum(sq);
    const float mu = s * 0.001953125f;
    const float var = sq * 0.001953125f - mu * mu;
    const float rs = rsqrtf(var + 1e-12f);
    const float4 g1 = *(const float4*)(gamma + (lane << 3));
    const float4 g2 = *(const float4*)(gamma + (lane << 3) + 4);
    const float4 b1 = *(const float4*)(beta + (lane << 3));
    const float4 b2 = *(const float4*)(beta + (lane << 3) + 4);
    float4 o1, o2;
    o1.x = (a.x - mu) * rs * g1.x + b1.x;
    o1.y = (a.y - mu) * rs * g1.y + b1.y;
    o1.z = (a.z - mu) * rs * g1.z + b1.z;
    o1.w = (a.w - mu) * rs * g1.w + b1.w;
    o2.x = (c.x - mu) * rs * g2.x + b2.x;
    o2.y = (c.y - mu) * rs * g2.y + b2.y;
    o2.z = (c.z - mu) * rs * g2.z + b2.z;
    o2.w = (c.w - mu) * rs * g2.w + b2.w;
    *(float4*)(out + (size_t)row * DMODEL + (lane << 3)) = o1;
    *(float4*)(out + (size_t)row * DMODEL + (lane << 3) + 4) = o2;
}

__global__ void init_misc(float* gmax)
{
    if (threadIdx.x == 0 && blockIdx.x == 0) *gmax = -1e30f;
}

// ---------------------------------------------------------------------------
extern "C" void kernel_launch(void* const* d_in, const int* in_sizes, int n_in,
                              void* d_out, int out_size, void* d_ws, size_t ws_size,
                              hipStream_t stream)
{
    const float* x     = (const float*)d_in[0];
    const float* Wq    = (const float*)d_in[2];
    const float* bq    = (const float*)d_in[3];
    const float* Wk    = (const float*)d_in[4];
    const float* bk    = (const float*)d_in[5];
    const float* Wv    = (const float*)d_in[6];
    const float* bv    = (const float*)d_in[7];
    const float* projq = (const float*)d_in[8];
    const float* projk = (const float*)d_in[9];
    const float* Wd    = (const float*)d_in[10];
    const float* bd    = (const float*)d_in[11];
    const float* gamma = (const float*)d_in[12];
    const float* beta  = (const float*)d_in[13];

    char* W = (char*)d_ws;
    bf16*  qb16   = (bf16*) (W);                   // 16 MB
    bf16*  kb16s  = (bf16*) (W + 16777216);        // 16 MB (swizzled rows)
    bf16*  vtb    = (bf16*) (W + 33554432);        // 16 MB (transposed+swizzled)
    bf16*  xb16   = (bf16*) (W + 50331648);        // 16 MB (x bf16, later ctx bf16)
    float* hidf32 = (float*)(W + 67108864);        // 32 MB
    bf16*  Wb16   = (bf16*) (W + 100663296);       // 1.5 MB
    bf16*  Wdb16  = (bf16*) (W + 102236160);       // 0.5 MB
    bf16*  pqb16  = (bf16*) (W + 102760448);       // 64 KB
    float* bcat   = (float*)(W + 102825984);       // 6 KB
    bf16*  ctxE   = (bf16*) (W + 102832128);       // 2,621,440 B  [32][80][512]
    float* vsumb  = (float*)(W + 105453568);       // 8 KB
    float* ctxsum = (float*)(W + 105461760);       // 8 KB
    float* esmsm  = (float*)(W + 105469952);       // 128 B
    float* gmaxb  = (float*)(W + 105470080);       // 4 B

    prep_convert<<<9250, 256, 0, stream>>>(x, Wq, Wk, Wv, Wd, projq, bq, bk, bv,
                                           xb16, Wb16, Wdb16, pqb16, bcat);
    hipMemsetAsync(ctxE, 0, 2621440, stream);                  // zero unused rows 66-79
    hipMemsetAsync(ctxsum, 0, 8192 + 128, stream);             // ctxsum + esumsum
    init_misc<<<1, 64, 0, stream>>>(gmaxb);

    gemm_mfma<0><<<dim3(12, 128), 256, 0, stream>>>(xb16, Wb16, bcat, nullptr,
                                                    qb16, kb16s, vtb, nullptr);

    vsum_kernel<<<2048, 64, 0, stream>>>(vtb, vsumb);
    kside_mfma<<<dim3(32, 8), 256, 0, stream>>>(kb16s, vtb, projk, ctxE,
                                                ctxsum, esmsm, gmaxb);
    qside_mfma2<<<dim3(32, 32), 256, 0, stream>>>(qb16, pqb16, ctxE, vsumb,
                                                  ctxsum, esmsm, gmaxb, xb16);

    gemm_mfma<1><<<dim3(4, 128), 256, 0, stream>>>(xb16, Wdb16, bd, x,
                                                   nullptr, nullptr, nullptr, hidf32);
    ln_kernel<<<16384, 64, 0, stream>>>(hidf32, gamma, beta, (float*)d_out);
}

// Round 5
// 242.691 us; speedup vs baseline: 7.6447x; 1.0053x over previous
//
#include <hip/hip_runtime.h>
#include <math.h>

typedef __bf16 bf16;
typedef __bf16 bf16x8 __attribute__((ext_vector_type(8)));
typedef __bf16 bf16x4 __attribute__((ext_vector_type(4)));
typedef float  f32x4  __attribute__((ext_vector_type(4)));

#define NSEQ 4096
#define DMODEL 512
#define DHEAD 64
#define MFEAT 512
#define BHEADS 32
#define ROWS_TOTAL 16384

#define NORMALIZER 0.35355339059327373f
#define DIAG_C 0.0625f
#define KEPS 1e-4f

__device__ __forceinline__ float warpReduceSum(float v) {
#pragma unroll
    for (int off = 32; off > 0; off >>= 1) v += __shfl_xor(v, off);
    return v;
}

__device__ __forceinline__ void atomicMaxF(float* addr, float val) {
    int* ai = (int*)addr;
    int cur = __float_as_int(*addr);
    while (__int_as_float(cur) < val) {
        int prev = atomicCAS(ai, cur, __float_as_int(val));
        if (prev == cur) break;
        cur = prev;
    }
}

__device__ __forceinline__ void gload16(const void* g, void* l) {
    __builtin_amdgcn_global_load_lds((const __attribute__((address_space(1))) void*)g,
                                     (__attribute__((address_space(3))) void*)l, 16, 0, 0);
}

// ---------------------------------------------------------------------------
// prep: f32 -> bf16 conversions + weight concat + bias concat
// ---------------------------------------------------------------------------
__global__ __launch_bounds__(256)
void prep_convert(const float* __restrict__ x, const float* __restrict__ Wq,
                  const float* __restrict__ Wk, const float* __restrict__ Wv,
                  const float* __restrict__ Wd, const float* __restrict__ pq,
                  const float* __restrict__ bq, const float* __restrict__ bk,
                  const float* __restrict__ bv,
                  bf16* __restrict__ xb, bf16* __restrict__ Wb,
                  bf16* __restrict__ Wdb, bf16* __restrict__ pqb,
                  float* __restrict__ bcat)
{
    size_t i4 = (size_t)blockIdx.x * 256 + threadIdx.x;
    size_t e0 = i4 * 4;
    if (e0 >= 9471488) return;
    const float* src;
    if (e0 < 8388608) {
        src = x + e0;
        float4 v = *(const float4*)src;
        bf16* d = xb + e0;
        d[0] = (bf16)v.x; d[1] = (bf16)v.y; d[2] = (bf16)v.z; d[3] = (bf16)v.w;
    } else if (e0 < 9175040) {
        size_t c = e0 - 8388608; int wsel = (int)(c >> 18); size_t o = c & 262143;
        src = (wsel == 0 ? Wq : wsel == 1 ? Wk : Wv) + o;
        float4 v = *(const float4*)src;
        bf16* d = Wb + c;
        d[0] = (bf16)v.x; d[1] = (bf16)v.y; d[2] = (bf16)v.z; d[3] = (bf16)v.w;
    } else if (e0 < 9437184) {
        size_t c = e0 - 9175040;
        src = Wd + c;
        float4 v = *(const float4*)src;
        bf16* d = Wdb + c;
        d[0] = (bf16)v.x; d[1] = (bf16)v.y; d[2] = (bf16)v.z; d[3] = (bf16)v.w;
    } else if (e0 < 9469952) {
        size_t c = e0 - 9437184;
        src = pq + c;
        float4 v = *(const float4*)src;
        bf16* d = pqb + c;
        d[0] = (bf16)v.x; d[1] = (bf16)v.y; d[2] = (bf16)v.z; d[3] = (bf16)v.w;
    } else {
        size_t c = e0 - 9469952; int wsel = (int)(c >> 9); size_t o = c & 511;
        src = (wsel == 0 ? bq : wsel == 1 ? bk : bv) + o;
        *(float4*)(bcat + c) = *(const float4*)src;
    }
}

// ---------------------------------------------------------------------------
// bf16 MFMA GEMM, C = A * B^T (+bias)(+resid), 128x128 tile, BK=64.
// MODE 0: A=xb16, B=Wcat[1536x512]; Q->bf16 plain; K->bf16 swizzled rows;
//         V->bf16 transposed [bh][e][n] swizzled.
// MODE 1: A=ctxb16, B=Wd; outF f32 = +bias +resid
// ---------------------------------------------------------------------------
template<int MODE>
__global__ __launch_bounds__(256)
void gemm_mfma(const bf16* __restrict__ A, const bf16* __restrict__ Bw,
               const float* __restrict__ bias, const float* __restrict__ resid,
               bf16* __restrict__ outQ, bf16* __restrict__ outK,
               bf16* __restrict__ outV, float* __restrict__ outF)
{
    __shared__ char As[16384];
    __shared__ char Bs[16384];
    const int tid = threadIdx.x;
    const int w = tid >> 6, l = tid & 63;
    const int wr = w >> 1, wc = w & 1;
    const int row0 = blockIdx.y << 7;
    const int col0 = blockIdx.x << 7;

    f32x4 acc[4][4] = {};
    const char* Ab = (const char*)A + (size_t)row0 * 1024;
    const char* Bb = (const char*)Bw + (size_t)col0 * 1024;

    for (int kt = 0; kt < 8; ++kt) {
        const int k0b = kt << 7;
#pragma unroll
        for (int i = 0; i < 4; ++i) {
            int off = (i << 12) + (tid << 4);
            int g = off ^ ((off >> 3) & 0x70);
            int grow = g >> 7, gcol = g & 127;
            gload16(Ab + (size_t)grow * 1024 + k0b + gcol, As + (i << 12) + (w << 10));
            gload16(Bb + (size_t)grow * 1024 + k0b + gcol, Bs + (i << 12) + (w << 10));
        }
        __syncthreads();
#pragma unroll
        for (int ks = 0; ks < 2; ++ks) {
            bf16x8 af[4], bb[4];
#pragma unroll
            for (int mi = 0; mi < 4; ++mi) {
                int row = (wr << 6) + (mi << 4) + (l & 15);
                int addr = ((row << 7) + (ks << 6) + ((l >> 4) << 4)) ^ ((row & 7) << 4);
                af[mi] = *(const bf16x8*)(As + addr);
            }
#pragma unroll
            for (int nj = 0; nj < 4; ++nj) {
                int row = (wc << 6) + (nj << 4) + (l & 15);
                int addr = ((row << 7) + (ks << 6) + ((l >> 4) << 4)) ^ ((row & 7) << 4);
                bb[nj] = *(const bf16x8*)(Bs + addr);
            }
#pragma unroll
            for (int mi = 0; mi < 4; ++mi)
#pragma unroll
                for (int nj = 0; nj < 4; ++nj)
                    acc[mi][nj] = __builtin_amdgcn_mfma_f32_16x16x32_bf16(af[mi], bb[nj], acc[mi][nj], 0, 0, 0);
        }
        __syncthreads();
    }

    const int subrow = (l >> 4) << 2;
    const int subcol = l & 15;
#pragma unroll
    for (int mi = 0; mi < 4; ++mi) {
#pragma unroll
        for (int nj = 0; nj < 4; ++nj) {
            const int cg = col0 + (wc << 6) + (nj << 4) + subcol;
            const float bi = bias[cg];
            const int rgb = row0 + (wr << 6) + (mi << 4) + subrow;
            if (MODE == 0) {
                if (cg < 512) {
#pragma unroll
                    for (int r = 0; r < 4; ++r)
                        outQ[(size_t)(rgb + r) * 512 + cg] = (bf16)(acc[mi][nj][r] + bi);
                } else if (cg < 1024) {
                    const int eg = cg - 512, hh = eg >> 6, ee = eg & 63;
#pragma unroll
                    for (int r = 0; r < 4; ++r) {
                        const int rg = rgb + r;
                        *(bf16*)((char*)outK + (size_t)rg * 1024 + hh * 128 +
                                 ((ee * 2) ^ ((rg & 7) << 4))) = (bf16)(acc[mi][nj][r] + bi);
                    }
                } else {
                    const int eg = cg - 1024, hh = eg >> 6, ee = eg & 63;
                    const int bb2 = rgb >> 12, n = rgb & 4095;
                    bf16x4 pv;
#pragma unroll
                    for (int r = 0; r < 4; ++r) pv[r] = (bf16)(acc[mi][nj][r] + bi);
                    const int nb = n * 2;
                    size_t byteaddr = (size_t)((bb2 * 8 + hh) * 64 + ee) * 8192
                                    + (size_t)((nb & ~127) | ((nb & 127) ^ ((ee & 7) << 4)));
                    *(bf16x4*)((char*)outV + byteaddr) = pv;
                }
            } else {
#pragma unroll
                for (int r = 0; r < 4; ++r) {
                    const int rg = rgb + r;
                    outF[(size_t)rg * 512 + cg] = acc[mi][nj][r] + bi + resid[(size_t)rg * 512 + cg];
                }
            }
        }
    }
}

// ---------------------------------------------------------------------------
// vsum[bh*64+e] = sum_n Vt[bh][e][n]. Grid 2048, block 64.
// ---------------------------------------------------------------------------
__global__ __launch_bounds__(64)
void vsum_kernel(const bf16* __restrict__ Vt, float* __restrict__ vsum)
{
    const int row = blockIdx.x;
    const bf16x8* p = (const bf16x8*)((const char*)Vt + (size_t)row * 8192);
    float s = 0.f;
#pragma unroll
    for (int i = 0; i < 8; ++i) {
        bf16x8 v = p[threadIdx.x + i * 64];
#pragma unroll
        for (int u = 0; u < 8; ++u) s += (float)v[u];
    }
    s = warpReduceSum(s);
    if (threadIdx.x == 0) vsum[row] = s;
}

// ---------------------------------------------------------------------------
// kside MFMA v2: grid (32 bh, 8 m-tiles(64), 4 n-slices), block 256.
// Each block: its 1024-n slice; writes PRIVATE f32 partials:
//   ctxp4[z][bh][m][e] (plain stores), esumf4[z][bh][m]; atomicMax gmax.
// ---------------------------------------------------------------------------
__global__ __launch_bounds__(256)
void kside_mfma2(const bf16* __restrict__ Kb, const bf16* __restrict__ Vt,
                 const float* __restrict__ projk,
                 float* __restrict__ ctxp4, float* __restrict__ esumf4,
                 float* __restrict__ gmax)
{
    __shared__ char K_s[16384];      // [128 n][128 B] swizzled
    __shared__ char V_s[16384];      // [64 e][256 B] swizzled
    __shared__ char E_s[16384];      // [64 m][256 B] swizzled
    __shared__ float diag_s[128];
    __shared__ float part_s[4][64];
    __shared__ float wmax_s[4];

    const int tid = threadIdx.x;
    const int w = tid >> 6, l = tid & 63;
    const int bh = blockIdx.x;
    const int b = bh >> 3, h = bh & 7;
    const int m0 = blockIdx.y << 6;
    const int z = blockIdx.z;

    bf16x8 pk[4][2];
#pragma unroll
    for (int nj = 0; nj < 4; ++nj)
#pragma unroll
        for (int ks = 0; ks < 2; ++ks) {
            const int m = m0 + (nj << 4) + (l & 15);
            const int e0 = (ks << 5) + ((l >> 4) << 3);
            const float* p = projk + (size_t)m * 64 + e0;
            float4 a = *(const float4*)p;
            float4 c = *(const float4*)(p + 4);
            bf16x8 f;
            f[0] = (bf16)a.x; f[1] = (bf16)a.y; f[2] = (bf16)a.z; f[3] = (bf16)a.w;
            f[4] = (bf16)c.x; f[5] = (bf16)c.y; f[6] = (bf16)c.z; f[7] = (bf16)c.w;
            pk[nj][ks] = f;
        }

    const char* kg = (const char*)Kb + ((size_t)(b * 4096) * 512 + h * 64) * 2
                   + (size_t)((w << 3) + (l >> 3)) * 1024 + ((l & 7) << 4);
    const char* vg = (const char*)Vt + (size_t)bh * 64 * 8192
                   + (size_t)((w << 2) + (l >> 4)) * 8192 + ((l & 15) << 4);

    float esacc[4] = {0.f, 0.f, 0.f, 0.f};
    float lmax = -1e30f;
    f32x4 acc2[4] = {};

    for (int c = 0; c < 8; ++c) {
        const int n0 = (z << 10) + (c << 7);
#pragma unroll
        for (int i = 0; i < 4; ++i) {
            gload16(kg + (size_t)(n0 + (i << 5)) * 1024, K_s + (i << 12) + (w << 10));
            gload16(vg + (size_t)(i << 4) * 8192 + (n0 << 1), V_s + (i << 12) + (w << 10));
        }
        __syncthreads();

        f32x4 acc1[2][4] = {};
        float ss[2] = {0.f, 0.f};
#pragma unroll
        for (int ks = 0; ks < 2; ++ks) {
            bf16x8 af[2];
#pragma unroll
            for (int mi = 0; mi < 2; ++mi) {
                const int n = (w << 5) + (mi << 4) + (l & 15);
                const int addr = ((n << 7) + (ks << 6) + ((l >> 4) << 4)) ^ ((n & 7) << 4);
                af[mi] = *(const bf16x8*)(K_s + addr);
#pragma unroll
                for (int u = 0; u < 8; ++u) { float f = (float)af[mi][u]; ss[mi] += f * f; }
            }
#pragma unroll
            for (int mi = 0; mi < 2; ++mi)
#pragma unroll
                for (int nj = 0; nj < 4; ++nj)
                    acc1[mi][nj] = __builtin_amdgcn_mfma_f32_16x16x32_bf16(af[mi], pk[nj][ks], acc1[mi][nj], 0, 0, 0);
        }
#pragma unroll
        for (int mi = 0; mi < 2; ++mi) {
            float s = ss[mi];
            s += __shfl_xor(s, 16); s += __shfl_xor(s, 32);
            if (l < 16) diag_s[(w << 5) + (mi << 4) + l] = DIAG_C * s;
        }
#pragma unroll
        for (int mi = 0; mi < 2; ++mi) {
            const int nrow0 = (w << 5) + (mi << 4) + ((l >> 4) << 2);
#pragma unroll
            for (int nj = 0; nj < 4; ++nj) {
                const int m = (nj << 4) + (l & 15);
                bf16x4 ev;
#pragma unroll
                for (int r = 0; r < 4; ++r) {
                    float kd = NORMALIZER * acc1[mi][nj][r];
                    lmax = fmaxf(lmax, kd);
                    float e = __expf(kd - diag_s[nrow0 + r]);
                    esacc[nj] += e;
                    ev[r] = (bf16)e;
                }
                const int addr = ((m << 8) + (nrow0 << 1)) ^ ((m & 7) << 4);
                *(bf16x4*)(E_s + addr) = ev;
            }
        }
        __syncthreads();

#pragma unroll
        for (int ks = 0; ks < 4; ++ks) {
            const int mrow = (w << 4) + (l & 15);
            const int aaddr = ((mrow << 8) + (ks << 6) + ((l >> 4) << 4)) ^ ((mrow & 7) << 4);
            bf16x8 aE = *(const bf16x8*)(E_s + aaddr);
#pragma unroll
            for (int ej = 0; ej < 4; ++ej) {
                const int e = (ej << 4) + (l & 15);
                const int vaddr = ((e << 8) + (ks << 6) + ((l >> 4) << 4)) ^ ((e & 7) << 4);
                bf16x8 bV = *(const bf16x8*)(V_s + vaddr);
                acc2[ej] = __builtin_amdgcn_mfma_f32_16x16x32_bf16(aE, bV, acc2[ej], 0, 0, 0);
            }
        }
        __syncthreads();
    }

    // ---- epilogue: private partial stores ----
#pragma unroll
    for (int nj = 0; nj < 4; ++nj) {
        float s = esacc[nj];
        s += __shfl_xor(s, 16); s += __shfl_xor(s, 32);
        if (l < 16) part_s[w][(nj << 4) + l] = s;
    }
#pragma unroll
    for (int off = 32; off > 0; off >>= 1) lmax = fmaxf(lmax, __shfl_xor(lmax, off));
    if (l == 0) wmax_s[w] = lmax;
    __syncthreads();
    if (tid < 64) {
        float es = part_s[0][tid] + part_s[1][tid] + part_s[2][tid] + part_s[3][tid];
        esumf4[((size_t)z * 32 + bh) * 512 + m0 + tid] = es;
        if (tid == 0)
            atomicMaxF(gmax, fmaxf(fmaxf(wmax_s[0], wmax_s[1]), fmaxf(wmax_s[2], wmax_s[3])));
    }
    const size_t zbase = (size_t)z * (32 * 512 * 64);
    const int mrow0 = m0 + (w << 4) + ((l >> 4) << 2);
#pragma unroll
    for (int ej = 0; ej < 4; ++ej) {
        const int e = (ej << 4) + (l & 15);
#pragma unroll
        for (int r = 0; r < 4; ++r)
            ctxp4[zbase + ((size_t)(bh * 512 + mrow0 + r)) * 64 + e] = acc2[ej][r];
    }
}

// ---------------------------------------------------------------------------
// finalize: sum 4 n-slice partials -> ctxE bf16 [bh][80][512] (rows 0-63 ctx^T,
// 64 ones, 65 esum), ctxsum (atomic over 4 m-chunks), esumsum.
// Grid (32 bh, 4 m-chunks), block 256.
// ---------------------------------------------------------------------------
__global__ __launch_bounds__(256)
void finalize_ctx(const float* __restrict__ ctxp4, const float* __restrict__ esumf4,
                  bf16* __restrict__ ctxE, float* __restrict__ ctxsum,
                  float* __restrict__ esumsum)
{
    __shared__ float red_s[4][64];
    const int tid = threadIdx.x;
    const int bh = blockIdx.x;
    const int m0 = blockIdx.y << 7;
    const int e = tid & 63, ms = tid >> 6;
    const size_t Z = (size_t)32 * 512 * 64;

    const float* cb = ctxp4 + ((size_t)bh * 512 + m0 + ms * 32) * 64 + e;
    bf16* ob = ctxE + (size_t)(bh * 80 + e) * 512 + m0 + ms * 32;
    float s = 0.f;
#pragma unroll
    for (int i8 = 0; i8 < 4; ++i8) {
        bf16x8 pk8;
#pragma unroll
        for (int u = 0; u < 8; ++u) {
            const size_t off = (size_t)(i8 * 8 + u) * 64;
            float v = cb[off] + cb[off + Z] + cb[off + 2 * Z] + cb[off + 3 * Z];
            s += v;
            pk8[u] = (bf16)v;
        }
        *(bf16x8*)((char*)ob + i8 * 16) = pk8;
    }
    red_s[ms][e] = s;
    __syncthreads();
    if (tid < 64)
        atomicAdd(ctxsum + bh * 64 + tid,
                  red_s[0][tid] + red_s[1][tid] + red_s[2][tid] + red_s[3][tid]);
    if (tid < 128) {
        const int m = m0 + tid;
        float ev = esumf4[(size_t)bh * 512 + m]
                 + esumf4[((size_t)32 + bh) * 512 + m]
                 + esumf4[((size_t)64 + bh) * 512 + m]
                 + esumf4[((size_t)96 + bh) * 512 + m];
        bf16* er = ctxE + (size_t)(bh * 80 + 64) * 512;
        er[m] = (bf16)1.0f;
        er[512 + m] = (bf16)ev;
        float t = warpReduceSum(ev);
        if ((tid & 63) == 0) atomicAdd(esumsum + bh, t);
    }
}

// ---------------------------------------------------------------------------
// q-side v3: phase-1 operands swapped (D[m][n]) -> per-lane diag, packed
// bf16x4 T_s writes, per-lane rowmax. Barrier-free, wave-private T_s rows.
// Grid (32 bh, 32 ntiles), block 256 (4 waves).
// ---------------------------------------------------------------------------
__global__ __launch_bounds__(256)
void qside_mfma3(const bf16* __restrict__ Qb, const bf16* __restrict__ Pq,
                 const bf16* __restrict__ CtxE, const float* __restrict__ vsum,
                 const float* __restrict__ ctxsum, const float* __restrict__ esumsum,
                 const float* __restrict__ gmax, bf16* __restrict__ OutC)
{
    __shared__ char T_s[128 * 272];   // [128 n][136 bf16], wave-private 32-row slices

    const int tid = threadIdx.x;
    const int w = tid >> 6, l = tid & 63;
    const int lq = l & 15, lg = l >> 4;
    const int bh = blockIdx.x;
    const int b = bh >> 3, h = bh & 7;
    const int n0 = blockIdx.y << 7;
    const int trow = (w << 5);

    // q as B-operand frags; diag per lane (col n = ni*16+lq)
    bf16x8 qf[2][2];
    float diag_l[2];
#pragma unroll
    for (int ni = 0; ni < 2; ++ni) {
        const int n = n0 + trow + (ni << 4) + lq;
        const char* qr = (const char*)Qb + ((size_t)(b * 4096 + n) * 512 + h * 64) * 2;
        float ss = 0.f;
#pragma unroll
        for (int ks = 0; ks < 2; ++ks) {
            qf[ni][ks] = *(const bf16x8*)(qr + (((ks << 5) + (lg << 3)) << 1));
#pragma unroll
            for (int u = 0; u < 8; ++u) { float f = (float)qf[ni][ks][u]; ss += f * f; }
        }
        ss += __shfl_xor(ss, 16);
        ss += __shfl_xor(ss, 32);
        diag_l[ni] = DIAG_C * ss;
    }

    f32x4 acc2[2][5] = {};
    float mmax[2] = {-1e30f, -1e30f};
    const char* ctxg = (const char*)CtxE + (size_t)bh * 80 * 512 * 2;

    for (int ft = 0; ft < 4; ++ft) {
        // phase 1: D[m][n] = projq . q^T  (K=64)
        f32x4 acc1[8][2] = {};
#pragma unroll
        for (int ks = 0; ks < 2; ++ks) {
#pragma unroll
            for (int mi = 0; mi < 8; ++mi) {
                const int feat = (ft << 7) + (mi << 4) + lq;
                bf16x8 pf = *(const bf16x8*)((const char*)Pq +
                              (((size_t)feat * 64 + (ks << 5) + (lg << 3)) << 1));
#pragma unroll
                for (int ni = 0; ni < 2; ++ni)
                    acc1[mi][ni] = __builtin_amdgcn_mfma_f32_16x16x32_bf16(pf, qf[ni][ks], acc1[mi][ni], 0, 0, 0);
            }
        }
        // exp -> T_s[n][m] (packed bf16x4 along m); per-lane rowmax
#pragma unroll
        for (int mi = 0; mi < 8; ++mi) {
#pragma unroll
            for (int ni = 0; ni < 2; ++ni) {
                bf16x4 tv;
#pragma unroll
                for (int r = 0; r < 4; ++r) {
                    const float qd = acc1[mi][ni][r];
                    mmax[ni] = fmaxf(mmax[ni], qd);
                    tv[r] = (bf16)__expf(NORMALIZER * qd - diag_l[ni]);
                }
                const int row = trow + (ni << 4) + lq;
                *(bf16x4*)(T_s + row * 272 + (((mi << 4) + (lg << 2)) << 1)) = tv;
            }
        }
        // phase 2: acc2 += T . ctxE^T (K=128 this ft; cols 64=ones,65=esum)
#pragma unroll
        for (int ks2 = 0; ks2 < 4; ++ks2) {
            bf16x8 ta[2];
#pragma unroll
            for (int ni = 0; ni < 2; ++ni) {
                const int row = trow + (ni << 4) + lq;
                ta[ni] = *(const bf16x8*)(T_s + row * 272 + (ks2 << 6) + (lg << 4));
            }
#pragma unroll
            for (int nj2 = 0; nj2 < 5; ++nj2) {
                const int e = (nj2 << 4) + lq;
                bf16x8 cbf = *(const bf16x8*)(ctxg +
                               (((size_t)e * 512 + (ft << 7) + (ks2 << 5) + (lg << 3)) << 1));
#pragma unroll
                for (int ni = 0; ni < 2; ++ni)
                    acc2[ni][nj2] = __builtin_amdgcn_mfma_f32_16x16x32_bf16(ta[ni], cbf, acc2[ni][nj2], 0, 0, 0);
            }
        }
    }

    // ---- epilogue: uT=col64, uE=col65, rowmax via shfl ----
    const float sG = __expf(-gmax[0]);
    const float ess = esumsum[bh];
    bf16* outb = OutC + ((size_t)(b * 4096 + n0)) * 512 + h * 64;
#pragma unroll
    for (int ni = 0; ni < 2; ++ni) {
        float mmr = mmax[ni];
        mmr = fmaxf(mmr, __shfl_xor(mmr, 16));
        mmr = fmaxf(mmr, __shfl_xor(mmr, 32));
#pragma unroll
        for (int r = 0; r < 4; ++r) {
            const float mm = __shfl(mmr, (lg << 2) + r);
            const float uT = __shfl(acc2[ni][4][r], l & 48);
            const float uE = __shfl(acc2[ni][4][r], (l & 48) | 1);
            const float cr = __expf(-NORMALIZER * mm);
            const float qsum = cr * uT + KEPS * 512.0f;
            const float D = sG * (cr * uE + KEPS * ess) + KEPS * 4096.0f * qsum;
            const float inv = 1.0f / D;
            const float al = sG * cr * inv;
            const float G1 = sG * KEPS * inv;
            const float G2 = KEPS * qsum * inv;
            const int row = trow + (ni << 4) + (lg << 2) + r;
#pragma unroll
            for (int nj2 = 0; nj2 < 4; ++nj2) {
                const int e = (nj2 << 4) + lq;
                float v = al * acc2[ni][nj2][r] + G1 * ctxsum[bh * 64 + e] + G2 * vsum[bh * 64 + e];
                outb[(size_t)row * 512 + e] = (bf16)v;
            }
        }
    }
}

// ---------------------------------------------------------------------------
// LayerNorm over D=512, 4 rows per 256-thread block. Grid 4096.
// ---------------------------------------------------------------------------
__global__ __launch_bounds__(256)
void ln_kernel(const float* __restrict__ hid, const float* __restrict__ gamma,
               const float* __restrict__ beta, float* __restrict__ out)
{
    const int row = (blockIdx.x << 2) + (threadIdx.x >> 6);
    const int lane = threadIdx.x & 63;
    const float* x = hid + (size_t)row * DMODEL + (lane << 3);
    float4 a = *(const float4*)x;
    float4 c = *(const float4*)(x + 4);
    float s = a.x + a.y + a.z + a.w + c.x + c.y + c.z + c.w;
    float sq = a.x * a.x + a.y * a.y + a.z * a.z + a.w * a.w +
               c.x * c.x + c.y * c.y + c.z * c.z + c.w * c.w;
    s = warpReduceSum(s);
    sq = warpReduceSum(sq);
    const float mu = s * 0.001953125f;
    const float var = sq * 0.001953125f - mu * mu;
    const float rs = rsqrtf(var + 1e-12f);
    const float4 g1 = *(const float4*)(gamma + (lane << 3));
    const float4 g2 = *(const float4*)(gamma + (lane << 3) + 4);
    const float4 b1 = *(const float4*)(beta + (lane << 3));
    const float4 b2 = *(const float4*)(beta + (lane << 3) + 4);
    float4 o1, o2;
    o1.x = (a.x - mu) * rs * g1.x + b1.x;
    o1.y = (a.y - mu) * rs * g1.y + b1.y;
    o1.z = (a.z - mu) * rs * g1.z + b1.z;
    o1.w = (a.w - mu) * rs * g1.w + b1.w;
    o2.x = (c.x - mu) * rs * g2.x + b2.x;
    o2.y = (c.y - mu) * rs * g2.y + b2.y;
    o2.z = (c.z - mu) * rs * g2.z + b2.z;
    o2.w = (c.w - mu) * rs * g2.w + b2.w;
    *(float4*)(out + (size_t)row * DMODEL + (lane << 3)) = o1;
    *(float4*)(out + (size_t)row * DMODEL + (lane << 3) + 4) = o2;
}

__global__ void init_misc(float* gmax)
{
    if (threadIdx.x == 0 && blockIdx.x == 0) *gmax = -1e30f;
}

// ---------------------------------------------------------------------------
extern "C" void kernel_launch(void* const* d_in, const int* in_sizes, int n_in,
                              void* d_out, int out_size, void* d_ws, size_t ws_size,
                              hipStream_t stream)
{
    const float* x     = (const float*)d_in[0];
    const float* Wq    = (const float*)d_in[2];
    const float* bq    = (const float*)d_in[3];
    const float* Wk    = (const float*)d_in[4];
    const float* bk    = (const float*)d_in[5];
    const float* Wv    = (const float*)d_in[6];
    const float* bv    = (const float*)d_in[7];
    const float* projq = (const float*)d_in[8];
    const float* projk = (const float*)d_in[9];
    const float* Wd    = (const float*)d_in[10];
    const float* bd    = (const float*)d_in[11];
    const float* gamma = (const float*)d_in[12];
    const float* beta  = (const float*)d_in[13];

    char* W = (char*)d_ws;
    bf16*  qb16   = (bf16*) (W);                   // 16 MB
    bf16*  kb16s  = (bf16*) (W + 16777216);        // 16 MB (swizzled rows)
    bf16*  vtb    = (bf16*) (W + 33554432);        // 16 MB (transposed+swizzled)
    bf16*  xb16   = (bf16*) (W + 50331648);        // 16 MB (x bf16, later ctx bf16)
    float* hidf32 = (float*)(W + 67108864);        // 32 MB (also aliases ctxp4/esumf4)
    float* ctxp4  = (float*)(W + 67108864);        // 16 MB  [4][32][512][64] f32 (dead before hid write)
    float* esumf4 = (float*)(W + 83886080);        // 256 KB [4][32][512] f32
    bf16*  Wb16   = (bf16*) (W + 100663296);       // 1.5 MB
    bf16*  Wdb16  = (bf16*) (W + 102236160);       // 0.5 MB
    bf16*  pqb16  = (bf16*) (W + 102760448);       // 64 KB
    float* bcat   = (float*)(W + 102825984);       // 6 KB
    bf16*  ctxE   = (bf16*) (W + 102832128);       // 2,621,440 B  [32][80][512]
    float* vsumb  = (float*)(W + 105453568);       // 8 KB
    float* ctxsum = (float*)(W + 105461760);       // 8 KB
    float* esmsm  = (float*)(W + 105469952);       // 128 B
    float* gmaxb  = (float*)(W + 105470080);       // 4 B

    prep_convert<<<9250, 256, 0, stream>>>(x, Wq, Wk, Wv, Wd, projq, bq, bk, bv,
                                           xb16, Wb16, Wdb16, pqb16, bcat);
    hipMemsetAsync(ctxE, 0, 2621440, stream);                  // zero rows 66-79
    hipMemsetAsync(ctxsum, 0, 8192 + 128, stream);             // ctxsum + esumsum
    init_misc<<<1, 64, 0, stream>>>(gmaxb);

    gemm_mfma<0><<<dim3(12, 128), 256, 0, stream>>>(xb16, Wb16, bcat, nullptr,
                                                    qb16, kb16s, vtb, nullptr);

    vsum_kernel<<<2048, 64, 0, stream>>>(vtb, vsumb);
    kside_mfma2<<<dim3(32, 8, 4), 256, 0, stream>>>(kb16s, vtb, projk,
                                                    ctxp4, esumf4, gmaxb);
    finalize_ctx<<<dim3(32, 4), 256, 0, stream>>>(ctxp4, esumf4, ctxE, ctxsum, esmsm);

    qside_mfma3<<<dim3(32, 32), 256, 0, stream>>>(qb16, pqb16, ctxE, vsumb,
                                                  ctxsum, esmsm, gmaxb, xb16);

    gemm_mfma<1><<<dim3(4, 128), 256, 0, stream>>>(xb16, Wdb16, bd, x,
                                                   nullptr, nullptr, nullptr, hidf32);
    ln_kernel<<<4096, 256, 0, stream>>>(hidf32, gamma, beta, (float*)d_out);
}

// Round 6
// 193.603 us; speedup vs baseline: 9.5830x; 1.2535x over previous
//
#include <hip/hip_runtime.h>
#include <math.h>

typedef __bf16 bf16;
typedef __bf16 bf16x8 __attribute__((ext_vector_type(8)));
typedef __bf16 bf16x4 __attribute__((ext_vector_type(4)));
typedef float  f32x4  __attribute__((ext_vector_type(4)));

#define NSEQ 4096
#define DMODEL 512
#define DHEAD 64
#define MFEAT 512
#define BHEADS 32
#define ROWS_TOTAL 16384

#define NORMALIZER 0.35355339059327373f
#define DIAG_C 0.0625f
#define KEPS 1e-4f

__device__ __forceinline__ float warpReduceSum(float v) {
#pragma unroll
    for (int off = 32; off > 0; off >>= 1) v += __shfl_xor(v, off);
    return v;
}

__device__ __forceinline__ void atomicMaxF(float* addr, float val) {
    int* ai = (int*)addr;
    int cur = __float_as_int(*addr);
    while (__int_as_float(cur) < val) {
        int prev = atomicCAS(ai, cur, __float_as_int(val));
        if (prev == cur) break;
        cur = prev;
    }
}

__device__ __forceinline__ void gload16(const void* g, void* l) {
    __builtin_amdgcn_global_load_lds((const __attribute__((address_space(1))) void*)g,
                                     (__attribute__((address_space(3))) void*)l, 16, 0, 0);
}

// ---------------------------------------------------------------------------
// prep: f32 -> bf16 conversions + weight concat + bias concat.
// pqb written PRE-SWIZZLED per 128B row: byte ^= (feat&7)<<4.
// ---------------------------------------------------------------------------
__global__ __launch_bounds__(256)
void prep_convert(const float* __restrict__ x, const float* __restrict__ Wq,
                  const float* __restrict__ Wk, const float* __restrict__ Wv,
                  const float* __restrict__ Wd, const float* __restrict__ pq,
                  const float* __restrict__ bq, const float* __restrict__ bk,
                  const float* __restrict__ bv,
                  bf16* __restrict__ xb, bf16* __restrict__ Wb,
                  bf16* __restrict__ Wdb, bf16* __restrict__ pqb,
                  float* __restrict__ bcat)
{
    size_t i4 = (size_t)blockIdx.x * 256 + threadIdx.x;
    size_t e0 = i4 * 4;
    if (e0 >= 9471488) return;
    const float* src;
    if (e0 < 8388608) {
        src = x + e0;
        float4 v = *(const float4*)src;
        bf16* d = xb + e0;
        d[0] = (bf16)v.x; d[1] = (bf16)v.y; d[2] = (bf16)v.z; d[3] = (bf16)v.w;
    } else if (e0 < 9175040) {
        size_t c = e0 - 8388608; int wsel = (int)(c >> 18); size_t o = c & 262143;
        src = (wsel == 0 ? Wq : wsel == 1 ? Wk : Wv) + o;
        float4 v = *(const float4*)src;
        bf16* d = Wb + c;
        d[0] = (bf16)v.x; d[1] = (bf16)v.y; d[2] = (bf16)v.z; d[3] = (bf16)v.w;
    } else if (e0 < 9437184) {
        size_t c = e0 - 9175040;
        src = Wd + c;
        float4 v = *(const float4*)src;
        bf16* d = Wdb + c;
        d[0] = (bf16)v.x; d[1] = (bf16)v.y; d[2] = (bf16)v.z; d[3] = (bf16)v.w;
    } else if (e0 < 9469952) {
        size_t c = e0 - 9437184;           // multiple of 4
        src = pq + c;
        float4 v = *(const float4*)src;
        const int feat = (int)(c >> 6), col = (int)(c & 63);
        bf16x4 d4;
        d4[0] = (bf16)v.x; d4[1] = (bf16)v.y; d4[2] = (bf16)v.z; d4[3] = (bf16)v.w;
        const int inrow = (col << 1) ^ ((feat & 7) << 4);
        *(bf16x4*)((char*)pqb + (size_t)feat * 128 + inrow) = d4;
    } else {
        size_t c = e0 - 9469952; int wsel = (int)(c >> 9); size_t o = c & 511;
        src = (wsel == 0 ? bq : wsel == 1 ? bk : bv) + o;
        *(float4*)(bcat + c) = *(const float4*)src;
    }
}

// ---------------------------------------------------------------------------
// bf16 MFMA GEMM, C = A * B^T (+bias)(+resid), 128x128 tile, BK=64.
// MODE 0: A=xb16, B=Wcat[1536x512]; Q->bf16 [bh][n][64]; K->bf16 swizzled rows;
//         V->bf16 transposed [bh][e][n] swizzled.
// MODE 1: A=ctxb16, B=Wd; outF f32 = +bias +resid
// ---------------------------------------------------------------------------
template<int MODE>
__global__ __launch_bounds__(256)
void gemm_mfma(const bf16* __restrict__ A, const bf16* __restrict__ Bw,
               const float* __restrict__ bias, const float* __restrict__ resid,
               bf16* __restrict__ outQ, bf16* __restrict__ outK,
               bf16* __restrict__ outV, float* __restrict__ outF)
{
    __shared__ char As[16384];
    __shared__ char Bs[16384];
    const int tid = threadIdx.x;
    const int w = tid >> 6, l = tid & 63;
    const int wr = w >> 1, wc = w & 1;
    const int row0 = blockIdx.y << 7;
    const int col0 = blockIdx.x << 7;

    f32x4 acc[4][4] = {};
    const char* Ab = (const char*)A + (size_t)row0 * 1024;
    const char* Bb = (const char*)Bw + (size_t)col0 * 1024;

    for (int kt = 0; kt < 8; ++kt) {
        const int k0b = kt << 7;
#pragma unroll
        for (int i = 0; i < 4; ++i) {
            int off = (i << 12) + (tid << 4);
            int g = off ^ ((off >> 3) & 0x70);
            int grow = g >> 7, gcol = g & 127;
            gload16(Ab + (size_t)grow * 1024 + k0b + gcol, As + (i << 12) + (w << 10));
            gload16(Bb + (size_t)grow * 1024 + k0b + gcol, Bs + (i << 12) + (w << 10));
        }
        __syncthreads();
#pragma unroll
        for (int ks = 0; ks < 2; ++ks) {
            bf16x8 af[4], bb[4];
#pragma unroll
            for (int mi = 0; mi < 4; ++mi) {
                int row = (wr << 6) + (mi << 4) + (l & 15);
                int addr = ((row << 7) + (ks << 6) + ((l >> 4) << 4)) ^ ((row & 7) << 4);
                af[mi] = *(const bf16x8*)(As + addr);
            }
#pragma unroll
            for (int nj = 0; nj < 4; ++nj) {
                int row = (wc << 6) + (nj << 4) + (l & 15);
                int addr = ((row << 7) + (ks << 6) + ((l >> 4) << 4)) ^ ((row & 7) << 4);
                bb[nj] = *(const bf16x8*)(Bs + addr);
            }
#pragma unroll
            for (int mi = 0; mi < 4; ++mi)
#pragma unroll
                for (int nj = 0; nj < 4; ++nj)
                    acc[mi][nj] = __builtin_amdgcn_mfma_f32_16x16x32_bf16(af[mi], bb[nj], acc[mi][nj], 0, 0, 0);
        }
        __syncthreads();
    }

    const int subrow = (l >> 4) << 2;
    const int subcol = l & 15;
#pragma unroll
    for (int mi = 0; mi < 4; ++mi) {
#pragma unroll
        for (int nj = 0; nj < 4; ++nj) {
            const int cg = col0 + (wc << 6) + (nj << 4) + subcol;
            const float bi = bias[cg];
            const int rgb = row0 + (wr << 6) + (mi << 4) + subrow;
            if (MODE == 0) {
                if (cg < 512) {
                    const int hh = cg >> 6, ee = cg & 63;
                    const int bb2 = rgb >> 12, n = rgb & 4095;
#pragma unroll
                    for (int r = 0; r < 4; ++r)
                        outQ[((size_t)((bb2 * 8 + hh) * 4096 + n + r)) * 64 + ee] =
                            (bf16)(acc[mi][nj][r] + bi);
                } else if (cg < 1024) {
                    const int eg = cg - 512, hh = eg >> 6, ee = eg & 63;
#pragma unroll
                    for (int r = 0; r < 4; ++r) {
                        const int rg = rgb + r;
                        *(bf16*)((char*)outK + (size_t)rg * 1024 + hh * 128 +
                                 ((ee * 2) ^ ((rg & 7) << 4))) = (bf16)(acc[mi][nj][r] + bi);
                    }
                } else {
                    const int eg = cg - 1024, hh = eg >> 6, ee = eg & 63;
                    const int bb2 = rgb >> 12, n = rgb & 4095;
                    bf16x4 pv;
#pragma unroll
                    for (int r = 0; r < 4; ++r) pv[r] = (bf16)(acc[mi][nj][r] + bi);
                    const int nb = n * 2;
                    size_t byteaddr = (size_t)((bb2 * 8 + hh) * 64 + ee) * 8192
                                    + (size_t)((nb & ~127) | ((nb & 127) ^ ((ee & 7) << 4)));
                    *(bf16x4*)((char*)outV + byteaddr) = pv;
                }
            } else {
#pragma unroll
                for (int r = 0; r < 4; ++r) {
                    const int rg = rgb + r;
                    outF[(size_t)rg * 512 + cg] = acc[mi][nj][r] + bi + resid[(size_t)rg * 512 + cg];
                }
            }
        }
    }
}

// ---------------------------------------------------------------------------
// vsum[bh*64+e] = sum_n Vt[bh][e][n]. Grid 2048, block 64.
// ---------------------------------------------------------------------------
__global__ __launch_bounds__(64)
void vsum_kernel(const bf16* __restrict__ Vt, float* __restrict__ vsum)
{
    const int row = blockIdx.x;
    const bf16x8* p = (const bf16x8*)((const char*)Vt + (size_t)row * 8192);
    float s = 0.f;
#pragma unroll
    for (int i = 0; i < 8; ++i) {
        bf16x8 v = p[threadIdx.x + i * 64];
#pragma unroll
        for (int u = 0; u < 8; ++u) s += (float)v[u];
    }
    s = warpReduceSum(s);
    if (threadIdx.x == 0) vsum[row] = s;
}

// ---------------------------------------------------------------------------
// kside MFMA: grid (32 bh, 8 m-tiles(64), 4 n-slices), block 256.
// Writes private f32 partials ctxp4[z], esumf4[z]; atomicMax gmax.
// ---------------------------------------------------------------------------
__global__ __launch_bounds__(256)
void kside_mfma2(const bf16* __restrict__ Kb, const bf16* __restrict__ Vt,
                 const float* __restrict__ projk,
                 float* __restrict__ ctxp4, float* __restrict__ esumf4,
                 float* __restrict__ gmax)
{
    __shared__ char K_s[16384];
    __shared__ char V_s[16384];
    __shared__ char E_s[16384];
    __shared__ float diag_s[128];
    __shared__ float part_s[4][64];
    __shared__ float wmax_s[4];

    const int tid = threadIdx.x;
    const int w = tid >> 6, l = tid & 63;
    const int bh = blockIdx.x;
    const int b = bh >> 3, h = bh & 7;
    const int m0 = blockIdx.y << 6;
    const int z = blockIdx.z;

    bf16x8 pk[4][2];
#pragma unroll
    for (int nj = 0; nj < 4; ++nj)
#pragma unroll
        for (int ks = 0; ks < 2; ++ks) {
            const int m = m0 + (nj << 4) + (l & 15);
            const int e0 = (ks << 5) + ((l >> 4) << 3);
            const float* p = projk + (size_t)m * 64 + e0;
            float4 a = *(const float4*)p;
            float4 c = *(const float4*)(p + 4);
            bf16x8 f;
            f[0] = (bf16)a.x; f[1] = (bf16)a.y; f[2] = (bf16)a.z; f[3] = (bf16)a.w;
            f[4] = (bf16)c.x; f[5] = (bf16)c.y; f[6] = (bf16)c.z; f[7] = (bf16)c.w;
            pk[nj][ks] = f;
        }

    const char* kg = (const char*)Kb + ((size_t)(b * 4096) * 512 + h * 64) * 2
                   + (size_t)((w << 3) + (l >> 3)) * 1024 + ((l & 7) << 4);
    const char* vg = (const char*)Vt + (size_t)bh * 64 * 8192
                   + (size_t)((w << 2) + (l >> 4)) * 8192 + ((l & 15) << 4);

    float esacc[4] = {0.f, 0.f, 0.f, 0.f};
    float lmax = -1e30f;
    f32x4 acc2[4] = {};

    for (int c = 0; c < 8; ++c) {
        const int n0 = (z << 10) + (c << 7);
#pragma unroll
        for (int i = 0; i < 4; ++i) {
            gload16(kg + (size_t)(n0 + (i << 5)) * 1024, K_s + (i << 12) + (w << 10));
            gload16(vg + (size_t)(i << 4) * 8192 + (n0 << 1), V_s + (i << 12) + (w << 10));
        }
        __syncthreads();

        f32x4 acc1[2][4] = {};
        float ss[2] = {0.f, 0.f};
#pragma unroll
        for (int ks = 0; ks < 2; ++ks) {
            bf16x8 af[2];
#pragma unroll
            for (int mi = 0; mi < 2; ++mi) {
                const int n = (w << 5) + (mi << 4) + (l & 15);
                const int addr = ((n << 7) + (ks << 6) + ((l >> 4) << 4)) ^ ((n & 7) << 4);
                af[mi] = *(const bf16x8*)(K_s + addr);
#pragma unroll
                for (int u = 0; u < 8; ++u) { float f = (float)af[mi][u]; ss[mi] += f * f; }
            }
#pragma unroll
            for (int mi = 0; mi < 2; ++mi)
#pragma unroll
                for (int nj = 0; nj < 4; ++nj)
                    acc1[mi][nj] = __builtin_amdgcn_mfma_f32_16x16x32_bf16(af[mi], pk[nj][ks], acc1[mi][nj], 0, 0, 0);
        }
#pragma unroll
        for (int mi = 0; mi < 2; ++mi) {
            float s = ss[mi];
            s += __shfl_xor(s, 16); s += __shfl_xor(s, 32);
            if (l < 16) diag_s[(w << 5) + (mi << 4) + l] = DIAG_C * s;
        }
#pragma unroll
        for (int mi = 0; mi < 2; ++mi) {
            const int nrow0 = (w << 5) + (mi << 4) + ((l >> 4) << 2);
#pragma unroll
            for (int nj = 0; nj < 4; ++nj) {
                const int m = (nj << 4) + (l & 15);
                bf16x4 ev;
#pragma unroll
                for (int r = 0; r < 4; ++r) {
                    float kd = NORMALIZER * acc1[mi][nj][r];
                    lmax = fmaxf(lmax, kd);
                    float e = __expf(kd - diag_s[nrow0 + r]);
                    esacc[nj] += e;
                    ev[r] = (bf16)e;
                }
                const int addr = ((m << 8) + (nrow0 << 1)) ^ ((m & 7) << 4);
                *(bf16x4*)(E_s + addr) = ev;
            }
        }
        __syncthreads();

#pragma unroll
        for (int ks = 0; ks < 4; ++ks) {
            const int mrow = (w << 4) + (l & 15);
            const int aaddr = ((mrow << 8) + (ks << 6) + ((l >> 4) << 4)) ^ ((mrow & 7) << 4);
            bf16x8 aE = *(const bf16x8*)(E_s + aaddr);
#pragma unroll
            for (int ej = 0; ej < 4; ++ej) {
                const int e = (ej << 4) + (l & 15);
                const int vaddr = ((e << 8) + (ks << 6) + ((l >> 4) << 4)) ^ ((e & 7) << 4);
                bf16x8 bV = *(const bf16x8*)(V_s + vaddr);
                acc2[ej] = __builtin_amdgcn_mfma_f32_16x16x32_bf16(aE, bV, acc2[ej], 0, 0, 0);
            }
        }
        __syncthreads();
    }

#pragma unroll
    for (int nj = 0; nj < 4; ++nj) {
        float s = esacc[nj];
        s += __shfl_xor(s, 16); s += __shfl_xor(s, 32);
        if (l < 16) part_s[w][(nj << 4) + l] = s;
    }
#pragma unroll
    for (int off = 32; off > 0; off >>= 1) lmax = fmaxf(lmax, __shfl_xor(lmax, off));
    if (l == 0) wmax_s[w] = lmax;
    __syncthreads();
    if (tid < 64) {
        float es = part_s[0][tid] + part_s[1][tid] + part_s[2][tid] + part_s[3][tid];
        esumf4[((size_t)z * 32 + bh) * 512 + m0 + tid] = es;
        if (tid == 0)
            atomicMaxF(gmax, fmaxf(fmaxf(wmax_s[0], wmax_s[1]), fmaxf(wmax_s[2], wmax_s[3])));
    }
    const size_t zbase = (size_t)z * (32 * 512 * 64);
    const int mrow0 = m0 + (w << 4) + ((l >> 4) << 2);
#pragma unroll
    for (int ej = 0; ej < 4; ++ej) {
        const int e = (ej << 4) + (l & 15);
#pragma unroll
        for (int r = 0; r < 4; ++r)
            ctxp4[zbase + ((size_t)(bh * 512 + mrow0 + r)) * 64 + e] = acc2[ej][r];
    }
}

// ---------------------------------------------------------------------------
// finalize: sum 4 partials -> ctxE bf16 [bh][80][1024B rows, PRE-SWIZZLED
// byte ^= (e&7)<<4]; rows 64=ones, 65=esum; ctxsum (atomic); esumsum.
// Grid (32 bh, 4 m-chunks), block 256.
// ---------------------------------------------------------------------------
__global__ __launch_bounds__(256)
void finalize_ctx(const float* __restrict__ ctxp4, const float* __restrict__ esumf4,
                  bf16* __restrict__ ctxE, float* __restrict__ ctxsum,
                  float* __restrict__ esumsum)
{
    __shared__ float red_s[4][64];
    const int tid = threadIdx.x;
    const int bh = blockIdx.x;
    const int m0 = blockIdx.y << 7;
    const int e = tid & 63, ms = tid >> 6;
    const size_t Z = (size_t)32 * 512 * 64;

    const float* cb = ctxp4 + ((size_t)bh * 512 + m0 + ms * 32) * 64 + e;
    char* obr = (char*)ctxE + ((size_t)bh * 80 + e) * 1024;
    float s = 0.f;
#pragma unroll
    for (int i8 = 0; i8 < 4; ++i8) {
        bf16x8 pk8;
#pragma unroll
        for (int u = 0; u < 8; ++u) {
            const size_t off = (size_t)(i8 * 8 + u) * 64;
            float v = cb[off] + cb[off + Z] + cb[off + 2 * Z] + cb[off + 3 * Z];
            s += v;
            pk8[u] = (bf16)v;
        }
        const int inrow = ((m0 + ms * 32 + i8 * 8) << 1) ^ ((e & 7) << 4);
        *(bf16x8*)(obr + inrow) = pk8;
    }
    red_s[ms][e] = s;
    __syncthreads();
    if (tid < 64)
        atomicAdd(ctxsum + bh * 64 + tid,
                  red_s[0][tid] + red_s[1][tid] + red_s[2][tid] + red_s[3][tid]);
    if (tid < 128) {
        const int m = m0 + tid;
        float ev = esumf4[(size_t)bh * 512 + m]
                 + esumf4[((size_t)32 + bh) * 512 + m]
                 + esumf4[((size_t)64 + bh) * 512 + m]
                 + esumf4[((size_t)96 + bh) * 512 + m];
        bf16* er = ctxE + (size_t)(bh * 80 + 64) * 512;
        er[m] = (bf16)1.0f;                 // row 64 (e&7==0: no swizzle)
        er[512 + (m ^ 8)] = (bf16)ev;       // row 65: byte (m*2)^16 => elem m^8
        float t = warpReduceSum(ev);
        if ((tid & 63) == 0) atomicAdd(esumsum + bh, t);
    }
}

// ---------------------------------------------------------------------------
// q-side v4: 512 threads (8 waves), 512 q-rows/block, grid (32 bh, 8).
// LDS: ctxE fully staged (80KB, swizzled), Pq double-buffered (2x16KB,
// swizzled), T per-wave slab buffer (stride-80B rows). q in registers.
// ---------------------------------------------------------------------------
__global__ __launch_bounds__(512, 1)
void qside_mfma4(const bf16* __restrict__ Qb, const bf16* __restrict__ Pq,
                 const bf16* __restrict__ CtxE, const float* __restrict__ vsum,
                 const float* __restrict__ ctxsum, const float* __restrict__ esumsum,
                 const float* __restrict__ gmax, bf16* __restrict__ OutC)
{
    __shared__ char ctx_s[81920];        // [80 e][1024B] swizzled
    __shared__ char pq_s[2][16384];      // [128 feat][128B] swizzled
    __shared__ char T_s[40960];          // 8 waves x 64 rows x 80B

    const int tid = threadIdx.x;
    const int w = tid >> 6, l = tid & 63;
    const int lq = l & 15, lg = l >> 4;
    const int bh = blockIdx.x;
    const int b = bh >> 3, h = bh & 7;
    const int n0 = blockIdx.y << 9;

    // ---- prologue staging ----
    const char* ctxg = (const char*)CtxE + (size_t)bh * 81920;
    const char* pqg  = (const char*)Pq;
#pragma unroll
    for (int i = 0; i < 10; ++i)
        gload16(ctxg + (i << 13) + (tid << 4), ctx_s + (i << 13) + (w << 10));
#pragma unroll
    for (int p = 0; p < 2; ++p)
        gload16(pqg + (p << 13) + (tid << 4), pq_s[0] + (p << 13) + (w << 10));

    // q fragments (B-operand) + per-lane diag (col n = ni*16+lq)
    const char* qgb = (const char*)Qb + ((size_t)bh * 4096 + n0 + (w << 6)) * 128;
    bf16x8 qa[4][2];
    float diag_l[4];
#pragma unroll
    for (int ni = 0; ni < 4; ++ni) {
        const char* qr = qgb + ((ni << 4) + lq) * 128;
        float ss = 0.f;
#pragma unroll
        for (int kk = 0; kk < 2; ++kk) {
            qa[ni][kk] = *(const bf16x8*)(qr + (kk << 6) + (lg << 4));
#pragma unroll
            for (int u = 0; u < 8; ++u) { float f = (float)qa[ni][kk][u]; ss += f * f; }
        }
        ss += __shfl_xor(ss, 16);
        ss += __shfl_xor(ss, 32);
        diag_l[ni] = DIAG_C * ss;
    }

    f32x4 acc2[4][5] = {};
    float mmax[4] = {-1e30f, -1e30f, -1e30f, -1e30f};
    char* tw = T_s + w * 5120;
    const f32x4 Zc = {0.f, 0.f, 0.f, 0.f};

    __syncthreads();

    for (int ft = 0; ft < 4; ++ft) {
        const int buf = ft & 1;
        if (ft < 3) {
#pragma unroll
            for (int p = 0; p < 2; ++p)
                gload16(pqg + ((ft + 1) << 14) + (p << 13) + (tid << 4),
                        pq_s[buf ^ 1] + (p << 13) + (w << 10));
        }
        const char* pqb = pq_s[buf];
#pragma unroll
        for (int sl = 0; sl < 4; ++sl) {
            // ---- phase 1: D[m][n] = projq . q^T, K=64, 32 m's ----
            f32x4 acc1[2][4];
#pragma unroll
            for (int mi = 0; mi < 2; ++mi) {
                const int fr = (sl << 5) + (mi << 4) + lq;
                bf16x8 pf = *(const bf16x8*)(pqb + fr * 128 +
                              (((lg << 4)) ^ ((lq & 7) << 4)));
#pragma unroll
                for (int ni = 0; ni < 4; ++ni)
                    acc1[mi][ni] = __builtin_amdgcn_mfma_f32_16x16x32_bf16(pf, qa[ni][0], Zc, 0, 0, 0);
            }
#pragma unroll
            for (int mi = 0; mi < 2; ++mi) {
                const int fr = (sl << 5) + (mi << 4) + lq;
                bf16x8 pf = *(const bf16x8*)(pqb + fr * 128 +
                              ((64 + (lg << 4)) ^ ((lq & 7) << 4)));
#pragma unroll
                for (int ni = 0; ni < 4; ++ni)
                    acc1[mi][ni] = __builtin_amdgcn_mfma_f32_16x16x32_bf16(pf, qa[ni][1], acc1[mi][ni], 0, 0, 0);
            }
            // ---- exp -> wave-private T_s slab ----
#pragma unroll
            for (int mi = 0; mi < 2; ++mi)
#pragma unroll
                for (int ni = 0; ni < 4; ++ni) {
                    bf16x4 tv;
#pragma unroll
                    for (int r = 0; r < 4; ++r) {
                        const float qd = acc1[mi][ni][r];
                        mmax[ni] = fmaxf(mmax[ni], qd);
                        tv[r] = (bf16)__expf(NORMALIZER * qd - diag_l[ni]);
                    }
                    *(bf16x4*)(tw + ((ni << 4) + lq) * 80 + (mi << 5) + (lg << 3)) = tv;
                }
            // ---- phase 2: acc2 += T . ctxE^T (32-k slab) ----
            bf16x8 ta[4];
#pragma unroll
            for (int ni = 0; ni < 4; ++ni)
                ta[ni] = *(const bf16x8*)(tw + ((ni << 4) + lq) * 80 + (lg << 4));
#pragma unroll
            for (int nj = 0; nj < 5; ++nj) {
                const int e = (nj << 4) + lq;
                bf16x8 cb = *(const bf16x8*)(ctx_s + e * 1024 +
                              (((ft << 8) + (sl << 6) + (lg << 4)) ^ ((e & 7) << 4)));
#pragma unroll
                for (int ni = 0; ni < 4; ++ni)
                    acc2[ni][nj] = __builtin_amdgcn_mfma_f32_16x16x32_bf16(ta[ni], cb, acc2[ni][nj], 0, 0, 0);
            }
        }
        __syncthreads();
    }

    // ---- epilogue: uT=col64, uE=col65 ----
    const float sG = __expf(-gmax[0]);
    const float ess = esumsum[bh];
    bf16* outb = OutC + ((size_t)(b * 4096) + n0 + (w << 6)) * 512 + (h << 6);
#pragma unroll
    for (int ni = 0; ni < 4; ++ni) {
        float mmr = mmax[ni];
        mmr = fmaxf(mmr, __shfl_xor(mmr, 16));
        mmr = fmaxf(mmr, __shfl_xor(mmr, 32));
#pragma unroll
        for (int r = 0; r < 4; ++r) {
            const float mm = __shfl(mmr, (lg << 2) + r);
            const float uT = __shfl(acc2[ni][4][r], (lg << 4));
            const float uE = __shfl(acc2[ni][4][r], (lg << 4) | 1);
            const float cr = __expf(-NORMALIZER * mm);
            const float qsum = cr * uT + KEPS * 512.0f;
            const float D = sG * (cr * uE + KEPS * ess) + KEPS * 4096.0f * qsum;
            const float inv = 1.0f / D;
            const float al = sG * cr * inv;
            const float G1 = sG * KEPS * inv;
            const float G2 = KEPS * qsum * inv;
            const int row = (ni << 4) + (lg << 2) + r;
#pragma unroll
            for (int nj = 0; nj < 4; ++nj) {
                const int e = (nj << 4) + lq;
                float v = al * acc2[ni][nj][r] + G1 * ctxsum[(bh << 6) + e] + G2 * vsum[(bh << 6) + e];
                outb[(size_t)row * 512 + e] = (bf16)v;
            }
        }
    }
}

// ---------------------------------------------------------------------------
// LayerNorm over D=512, 4 rows per 256-thread block. Grid 4096.
// ---------------------------------------------------------------------------
__global__ __launch_bounds__(256)
void ln_kernel(const float* __restrict__ hid, const float* __restrict__ gamma,
               const float* __restrict__ beta, float* __restrict__ out)
{
    const int row = (blockIdx.x << 2) + (threadIdx.x >> 6);
    const int lane = threadIdx.x & 63;
    const float* x = hid + (size_t)row * DMODEL + (lane << 3);
    float4 a = *(const float4*)x;
    float4 c = *(const float4*)(x + 4);
    float s = a.x + a.y + a.z + a.w + c.x + c.y + c.z + c.w;
    float sq = a.x * a.x + a.y * a.y + a.z * a.z + a.w * a.w +
               c.x * c.x + c.y * c.y + c.z * c.z + c.w * c.w;
    s = warpReduceSum(s);
    sq = warpReduceSum(sq);
    const float mu = s * 0.001953125f;
    const float var = sq * 0.001953125f - mu * mu;
    const float rs = rsqrtf(var + 1e-12f);
    const float4 g1 = *(const float4*)(gamma + (lane << 3));
    const float4 g2 = *(const float4*)(gamma + (lane << 3) + 4);
    const float4 b1 = *(const float4*)(beta + (lane << 3));
    const float4 b2 = *(const float4*)(beta + (lane << 3) + 4);
    float4 o1, o2;
    o1.x = (a.x - mu) * rs * g1.x + b1.x;
    o1.y = (a.y - mu) * rs * g1.y + b1.y;
    o1.z = (a.z - mu) * rs * g1.z + b1.z;
    o1.w = (a.w - mu) * rs * g1.w + b1.w;
    o2.x = (c.x - mu) * rs * g2.x + b2.x;
    o2.y = (c.y - mu) * rs * g2.y + b2.y;
    o2.z = (c.z - mu) * rs * g2.z + b2.z;
    o2.w = (c.w - mu) * rs * g2.w + b2.w;
    *(float4*)(out + (size_t)row * DMODEL + (lane << 3)) = o1;
    *(float4*)(out + (size_t)row * DMODEL + (lane << 3) + 4) = o2;
}

__global__ void init_misc(float* gmax)
{
    if (threadIdx.x == 0 && blockIdx.x == 0) *gmax = -1e30f;
}

// ---------------------------------------------------------------------------
extern "C" void kernel_launch(void* const* d_in, const int* in_sizes, int n_in,
                              void* d_out, int out_size, void* d_ws, size_t ws_size,
                              hipStream_t stream)
{
    const float* x     = (const float*)d_in[0];
    const float* Wq    = (const float*)d_in[2];
    const float* bq    = (const float*)d_in[3];
    const float* Wk    = (const float*)d_in[4];
    const float* bk    = (const float*)d_in[5];
    const float* Wv    = (const float*)d_in[6];
    const float* bv    = (const float*)d_in[7];
    const float* projq = (const float*)d_in[8];
    const float* projk = (const float*)d_in[9];
    const float* Wd    = (const float*)d_in[10];
    const float* bd    = (const float*)d_in[11];
    const float* gamma = (const float*)d_in[12];
    const float* beta  = (const float*)d_in[13];

    char* W = (char*)d_ws;
    bf16*  qb16   = (bf16*) (W);                   // 16 MB  [bh][n][64]
    bf16*  kb16s  = (bf16*) (W + 16777216);        // 16 MB (swizzled rows)
    bf16*  vtb    = (bf16*) (W + 33554432);        // 16 MB (transposed+swizzled)
    bf16*  xb16   = (bf16*) (W + 50331648);        // 16 MB (x bf16, later ctx bf16)
    float* hidf32 = (float*)(W + 67108864);        // 32 MB (aliases ctxp4/esumf4)
    float* ctxp4  = (float*)(W + 67108864);        // 16 MB  [4][32][512][64] f32
    float* esumf4 = (float*)(W + 83886080);        // 256 KB [4][32][512] f32
    bf16*  Wb16   = (bf16*) (W + 100663296);       // 1.5 MB
    bf16*  Wdb16  = (bf16*) (W + 102236160);       // 0.5 MB
    bf16*  pqb16  = (bf16*) (W + 102760448);       // 64 KB (pre-swizzled)
    float* bcat   = (float*)(W + 102825984);       // 6 KB
    bf16*  ctxE   = (bf16*) (W + 102832128);       // 2,621,440 B [32][80][512] swz
    float* vsumb  = (float*)(W + 105453568);       // 8 KB
    float* ctxsum = (float*)(W + 105461760);       // 8 KB
    float* esmsm  = (float*)(W + 105469952);       // 128 B
    float* gmaxb  = (float*)(W + 105470080);       // 4 B

    prep_convert<<<9250, 256, 0, stream>>>(x, Wq, Wk, Wv, Wd, projq, bq, bk, bv,
                                           xb16, Wb16, Wdb16, pqb16, bcat);
    hipMemsetAsync(ctxE, 0, 2621440, stream);                  // zero rows 66-79
    hipMemsetAsync(ctxsum, 0, 8192 + 128, stream);             // ctxsum + esumsum
    init_misc<<<1, 64, 0, stream>>>(gmaxb);

    gemm_mfma<0><<<dim3(12, 128), 256, 0, stream>>>(xb16, Wb16, bcat, nullptr,
                                                    qb16, kb16s, vtb, nullptr);

    vsum_kernel<<<2048, 64, 0, stream>>>(vtb, vsumb);
    kside_mfma2<<<dim3(32, 8, 4), 256, 0, stream>>>(kb16s, vtb, projk,
                                                    ctxp4, esumf4, gmaxb);
    finalize_ctx<<<dim3(32, 4), 256, 0, stream>>>(ctxp4, esumf4, ctxE, ctxsum, esmsm);

    qside_mfma4<<<dim3(32, 8), 512, 0, stream>>>(qb16, pqb16, ctxE, vsumb,
                                                 ctxsum, esmsm, gmaxb, xb16);

    gemm_mfma<1><<<dim3(4, 128), 256, 0, stream>>>(xb16, Wdb16, bd, x,
                                                   nullptr, nullptr, nullptr, hidf32);
    ln_kernel<<<4096, 256, 0, stream>>>(hidf32, gamma, beta, (float*)d_out);
}